// Round 1
// baseline (274.416 us; speedup 1.0000x reference)
//
#include <hip/hip_runtime.h>
#include <hip/hip_bf16.h>

// Problem constants (fixed shapes)
#define BATCH 2
#define SEQ   2048
#define EMB   1024
#define DATTN 1024
#define NH    16
#define HD    64
#define MM    (BATCH*SEQ)        // 4096 rows
#define SCALE 0.03125f           // 1/sqrt(1024), exact power of 2
#define MINIT -1.0e30f
#define ROPE_COEF 0.41524101186f // (2/64)*log2(10000)

using bf16x8 = __attribute__((ext_vector_type(8))) short;   // 8 bf16 (4 VGPRs)
using f32x4  = __attribute__((ext_vector_type(4))) float;   // MFMA C/D

__device__ inline short f2bf(float x) {
    __hip_bfloat16 b = __float2bfloat16(x);
    return *reinterpret_cast<short*>(&b);
}

// async global->LDS, 16 B per lane (wave-uniform LDS base). [m03/m97]
__device__ inline void gl_lds16(const short* g, short* l) {
    __builtin_amdgcn_global_load_lds(
        (const __attribute__((address_space(1))) unsigned int*)g,
        (__attribute__((address_space(3))) unsigned int*)l, 16, 0, 0);
}

// ---------------- fp32 -> bf16 pre-convert (q,k,v,Wq,Wk,Wv,Wo) ----------------
__global__ __launch_bounds__(256)
void cvt_all(const float* __restrict__ q, const float* __restrict__ k,
             const float* __restrict__ v,
             const float* __restrict__ Wq, const float* __restrict__ Wk,
             const float* __restrict__ Wv, const float* __restrict__ Wo,
             short* __restrict__ dst)
{
    const long QKV = (long)MM * EMB;      // 4,194,304
    const long WSZ = (long)DATTN * EMB;   // 1,048,576
    const long i = ((long)blockIdx.x * 256 + threadIdx.x) * 4;
    const float* s;
    long off;
    if (i < 3 * QKV) {
        const int seg = (int)(i / QKV);
        off = i - (long)seg * QKV;
        s = (seg == 0) ? q : (seg == 1) ? k : v;
    } else {
        const long j = i - 3 * QKV;
        const int seg = (int)(j / WSZ);
        off = j - (long)seg * WSZ;
        s = (seg == 0) ? Wq : (seg == 1) ? Wk : (seg == 2) ? Wv : Wo;
    }
    float4 x = *(const float4*)(s + off);
    short4 y;
    y.x = f2bf(x.x); y.y = f2bf(x.y); y.z = f2bf(x.z); y.w = f2bf(x.w);
    *(short4*)(dst + i) = y;
}

// ---------------- bf16 MFMA GEMM: 128x128 tile, BK=32, global_load_lds staging ----------------
__device__ inline void stage_tile(const short* g, short* lds, int wave, int lane) {
    #pragma unroll
    for (int qq = 0; qq < 2; ++qq) {
        const int r = wave * 32 + qq * 16 + (lane >> 2);
        gl_lds16(g + (long)r * EMB + (lane & 3) * 8, lds + (wave * 2 + qq) * 512);
    }
}

// Fused Q/K/V projection with RoPE fused into the epilogue for Q/K.
__global__ __launch_bounds__(256)
void gemm_proj_bf16(const short* __restrict__ qb, const short* __restrict__ kb,
                    const short* __restrict__ vb,
                    const short* __restrict__ wqb, const short* __restrict__ wkb,
                    const short* __restrict__ wvb,
                    short* __restrict__ Qb, short* __restrict__ Kb,
                    short* __restrict__ Vtb)
{
    const short* A; const short* B;
    if (blockIdx.z == 0)      { A = qb; B = wqb; }
    else if (blockIdx.z == 1) { A = kb; B = wkb; }
    else                      { A = vb; B = wvb; }

    __shared__ short sA[128 * 32];
    __shared__ short sB[128 * 32];

    const int tid  = threadIdx.x;
    const int wave = tid >> 6, lane = tid & 63;
    const int quad = lane >> 4, l16 = lane & 15;
    const int wm = (wave >> 1) * 64, wn = (wave & 1) * 64;
    const long m0 = (long)blockIdx.x * 128, n0 = (long)blockIdx.y * 128;

    f32x4 acc[4][4];
    #pragma unroll
    for (int i = 0; i < 4; ++i)
        #pragma unroll
        for (int j = 0; j < 4; ++j) acc[i][j] = (f32x4){0.f, 0.f, 0.f, 0.f};

    for (int kt = 0; kt < EMB; kt += 32) {
        __syncthreads();
        stage_tile(A + m0 * EMB + kt, sA, wave, lane);
        stage_tile(B + n0 * EMB + kt, sB, wave, lane);
        __syncthreads();

        bf16x8 af[4], bfr[4];
        #pragma unroll
        for (int rt = 0; rt < 4; ++rt)
            af[rt] = *(const bf16x8*)&sA[(wm + rt * 16 + l16) * 32 + quad * 8];
        #pragma unroll
        for (int ct = 0; ct < 4; ++ct)
            bfr[ct] = *(const bf16x8*)&sB[(wn + ct * 16 + l16) * 32 + quad * 8];
        #pragma unroll
        for (int rt = 0; rt < 4; ++rt)
            #pragma unroll
            for (int ct = 0; ct < 4; ++ct)
                acc[rt][ct] = __builtin_amdgcn_mfma_f32_16x16x32_bf16(
                    af[rt], bfr[ct], acc[rt][ct], 0, 0, 0);
    }

    if (blockIdx.z < 2) {
        // Q/K: fused RoPE (pair lives in adjacent l16 lanes -> shfl_xor(.,1))
        short* C = (blockIdx.z == 0) ? Qb : Kb;
        const float scl = (blockIdx.z == 0) ? SCALE : 1.0f;
        const int odd = l16 & 1;
        #pragma unroll
        for (int ct = 0; ct < 4; ++ct) {
            const long col = n0 + wn + ct * 16 + l16;
            const int hh = (int)(col >> 6), dd = (int)(col & (HD - 1));
            const float invf = exp2f(-ROPE_COEF * (float)(dd >> 1));
            #pragma unroll
            for (int rt = 0; rt < 4; ++rt) {
                #pragma unroll
                for (int reg = 0; reg < 4; ++reg) {
                    const long row = m0 + wm + rt * 16 + quad * 4 + reg;
                    const int bb = (int)(row >> 11), ss = (int)(row & (SEQ - 1));
                    const float val = acc[rt][ct][reg];
                    const float prt = __shfl_xor(val, 1, 64);
                    float sn, cs;
                    __sincosf((float)ss * invf, &sn, &cs);
                    const float o = odd ? (prt * sn + val * cs)
                                        : (val * cs - prt * sn);
                    C[(((long)(bb * NH + hh)) << 17) + ((long)ss << 6) + dd] =
                        f2bf(o * scl);
                }
            }
        }
    } else {
        // V transposed: Vt[((b*NH+h)*HD + d)*SEQ + s]
        #pragma unroll
        for (int rt = 0; rt < 4; ++rt) {
            #pragma unroll
            for (int ct = 0; ct < 4; ++ct) {
                const long row0 = m0 + wm + rt * 16 + quad * 4;
                const long col  = n0 + wn + ct * 16 + l16;
                const int bb = (int)(row0 >> 11), ss = (int)(row0 & (SEQ - 1));
                const int hh = (int)(col >> 6),   dd = (int)(col & (HD - 1));
                short4 s4;
                s4.x = f2bf(acc[rt][ct][0]); s4.y = f2bf(acc[rt][ct][1]);
                s4.z = f2bf(acc[rt][ct][2]); s4.w = f2bf(acc[rt][ct][3]);
                *(short4*)&Vtb[(((long)(bb * NH + hh)) << 17) + ((long)dd << 11) + ss] = s4;
            }
        }
    }
}

// Output GEMM: out = ctx(bf16) @ Wo^T(bf16), out fp32 [4096,1024]
__global__ __launch_bounds__(256)
void gemm_out_bf16(const short* __restrict__ Ab, const short* __restrict__ Bb,
                   float* __restrict__ C)
{
    __shared__ short sA[128 * 32];
    __shared__ short sB[128 * 32];

    const int tid  = threadIdx.x;
    const int wave = tid >> 6, lane = tid & 63;
    const int quad = lane >> 4, l16 = lane & 15;
    const int wm = (wave >> 1) * 64, wn = (wave & 1) * 64;
    const long m0 = (long)blockIdx.x * 128, n0 = (long)blockIdx.y * 128;

    f32x4 acc[4][4];
    #pragma unroll
    for (int i = 0; i < 4; ++i)
        #pragma unroll
        for (int j = 0; j < 4; ++j) acc[i][j] = (f32x4){0.f, 0.f, 0.f, 0.f};

    for (int kt = 0; kt < DATTN; kt += 32) {
        __syncthreads();
        stage_tile(Ab + m0 * DATTN + kt, sA, wave, lane);
        stage_tile(Bb + n0 * DATTN + kt, sB, wave, lane);
        __syncthreads();

        bf16x8 af[4], bfr[4];
        #pragma unroll
        for (int rt = 0; rt < 4; ++rt)
            af[rt] = *(const bf16x8*)&sA[(wm + rt * 16 + l16) * 32 + quad * 8];
        #pragma unroll
        for (int ct = 0; ct < 4; ++ct)
            bfr[ct] = *(const bf16x8*)&sB[(wn + ct * 16 + l16) * 32 + quad * 8];
        #pragma unroll
        for (int rt = 0; rt < 4; ++rt)
            #pragma unroll
            for (int ct = 0; ct < 4; ++ct)
                acc[rt][ct] = __builtin_amdgcn_mfma_f32_16x16x32_bf16(
                    af[rt], bfr[ct], acc[rt][ct], 0, 0, 0);
    }

    #pragma unroll
    for (int rt = 0; rt < 4; ++rt) {
        #pragma unroll
        for (int ct = 0; ct < 4; ++ct) {
            #pragma unroll
            for (int reg = 0; reg < 4; ++reg) {
                const long row = m0 + wm + rt * 16 + quad * 4 + reg;
                const long col = n0 + wn + ct * 16 + l16;
                C[row * EMB + col] = acc[rt][ct][reg];
            }
        }
    }
}

// ---------------- MFMA flash attention: balanced dual-tile, async-staged ----------------
// 512 blocks; block = (pair p, tile-pair {tA, tB=31-tA}). rounds(t)=floor(t/2)+1 so
// rounds(tA)+rounds(tB)=17 for EVERY block -> perfect compute balance, grid = exactly
// 2 blocks/CU, all co-resident (no dispatch tail). Each wave runs TWO independent
// softmax/acc streams (tiles A and B) -> 2x ILP; while jt2<=tA both streams share the
// same staged K/V fragments (LDS reads amortized 2x). T14 async-STAGE: next round's
// global->reg loads issue right after the staging barrier and retire under compute.
// XCD pinning: id&7 = residue; 4 pairs/XCD -> 2 MB K+V L2-resident (R12-verified).
// LDS 55.3 KB -> 2 blocks/CU; VGPR target < 256 (2 waves/SIMD).
#define LDP 72

__global__ __launch_bounds__(256, 2)
void flash_attn_mfma(const short* __restrict__ Qb,
                     const short* __restrict__ Kb,
                     const short* __restrict__ Vtb,
                     short* __restrict__ ctx)
{
    // id -> (xcd residue r, pair p, tile pair tA/tB)
    const int id = blockIdx.x;            // 0..511
    const int r  = id & 7;
    const int q6 = id >> 3;               // 0..63
    const int ta = q6 & 15;               // 16 tile-pairs
    const int pi = q6 >> 4;               // 4 pairs per residue
    const int p  = r + 8 * pi;            // (b*NH+h) in [0,32)
    const int b  = p >> 4, h = p & 15;
    const int tA = ta;                    // light tile  (0..15)
    const int tB = 31 - ta;               // heavy tile (16..31)
    const int tid = threadIdx.x;
    const int wave = tid >> 6, lane = tid & 63;
    const int quad = lane >> 4, l16 = lane & 15;

    __shared__ short sk2[2][64 * LDP];
    __shared__ short sv2[2][64 * LDP];
    __shared__ short spA[4][16 * LDP];
    __shared__ short spB[4][16 * LDP];

    const long base = ((long)(b * NH + h)) << 17;   // SEQ*HD = 2^17

    // Q fragments (B operand): row l16 = query, k = quad*8 (+tt*32)
    const int iqA = tA * 64 + wave * 16 + l16;
    const int iqB = tB * 64 + wave * 16 + l16;
    bf16x8 qfA[2], qfB[2];
    #pragma unroll
    for (int tt = 0; tt < 2; ++tt) {
        qfA[tt] = *(const bf16x8*)(Qb + base + (long)iqA * HD + tt * 32 + quad * 8);
        qfB[tt] = *(const bf16x8*)(Qb + base + (long)iqB * HD + tt * 32 + quad * 8);
    }

    f32x4 accA[4], accB[4];
    #pragma unroll
    for (int ct = 0; ct < 4; ++ct) {
        accA[ct] = (f32x4){0.f, 0.f, 0.f, 0.f};
        accB[ct] = (f32x4){0.f, 0.f, 0.f, 0.f};
    }
    float mqA = MINIT, lqA = 0.f, mqB = MINIT, lqB = 0.f;

    // rounds follow the heavy tile: nr = floor(tB/2)+1 in [9,16]
    const int nr = (tB + 2) >> 1;

    // one 64-key half-tile step for one stream (verified fragment math, unchanged)
    auto attn_tile = [&](const bf16x8 (&kf)[4][2], const bf16x8 (&vf)[4][2],
                         const bf16x8 (&qf)[2], f32x4 (&acc)[4],
                         float& mq, float& lq, short* pw,
                         int jb2, int iq, bool diag) {
        // S^T: C-layout col=l16=query, row=quad*4+reg=key
        f32x4 s[4];
        #pragma unroll
        for (int ct = 0; ct < 4; ++ct) {
            f32x4 z = (f32x4){0.f, 0.f, 0.f, 0.f};
            z = __builtin_amdgcn_mfma_f32_16x16x32_bf16(kf[ct][0], qf[0], z, 0, 0, 0);
            z = __builtin_amdgcn_mfma_f32_16x16x32_bf16(kf[ct][1], qf[1], z, 0, 0, 0);
            s[ct] = z;
        }

        if (diag) {   // diagonal tile: apply causal mask
            #pragma unroll
            for (int ct = 0; ct < 4; ++ct)
                #pragma unroll
                for (int rr = 0; rr < 4; ++rr) {
                    const int j = jb2 + ct * 16 + quad * 4 + rr;
                    const bool ok = (j < iq) || (iq == 0 && j == 0);
                    if (!ok) s[ct][rr] = -INFINITY;
                }
        }

        float mx = MINIT;
        #pragma unroll
        for (int ct = 0; ct < 4; ++ct)
            #pragma unroll
            for (int rr = 0; rr < 4; ++rr) mx = fmaxf(mx, s[ct][rr]);
        mx = fmaxf(mx, __shfl_xor(mx, 16, 64));
        mx = fmaxf(mx, __shfl_xor(mx, 32, 64));
        const float mn = fmaxf(mq, mx);
        const float alpha = __expf(mq - mn);
        mq = mn;
        float ss = 0.f;
        #pragma unroll
        for (int ct = 0; ct < 4; ++ct)
            #pragma unroll
            for (int rr = 0; rr < 4; ++rr) {
                const float e = __expf(s[ct][rr] - mn);
                s[ct][rr] = e;
                ss += e;
            }
        ss += __shfl_xor(ss, 16, 64);
        ss += __shfl_xor(ss, 32, 64);
        lq = lq * alpha + ss;

        #pragma unroll
        for (int ct = 0; ct < 4; ++ct) {
            short4 p4;
            p4.x = f2bf(s[ct][0]); p4.y = f2bf(s[ct][1]);
            p4.z = f2bf(s[ct][2]); p4.w = f2bf(s[ct][3]);
            *(short4*)&pw[l16 * LDP + ct * 16 + quad * 4] = p4;
        }

        #pragma unroll
        for (int ct = 0; ct < 4; ++ct)
            #pragma unroll
            for (int rr = 0; rr < 4; ++rr) acc[ct][rr] *= alpha;

        bf16x8 pf0 = *(const bf16x8*)&pw[l16 * LDP + quad * 8];
        bf16x8 pf1 = *(const bf16x8*)&pw[l16 * LDP + 32 + quad * 8];
        #pragma unroll
        for (int ct = 0; ct < 4; ++ct) {
            acc[ct] = __builtin_amdgcn_mfma_f32_16x16x32_bf16(
                vf[ct][0], pf0, acc[ct], 0, 0, 0);
            acc[ct] = __builtin_amdgcn_mfma_f32_16x16x32_bf16(
                vf[ct][1], pf1, acc[ct], 0, 0, 0);
        }
    };

    // T14 async-STAGE: global loads -> regs (issue early), LDS writes (late)
    int4 rK[4], rV[4];
    auto load_stage = [&](int jt) {
        const int jbase = jt * 128;
        #pragma unroll
        for (int c = 0; c < 4; ++c) {
            const int cc   = c * 256 + tid;
            const int half = cc >> 9;
            const int row  = (cc >> 3) & 63;
            const int off  = (cc & 7) * 8;
            rK[c] = *(const int4*)(Kb + base
                + (long)(jbase + half * 64 + row) * HD + off);
            rV[c] = *(const int4*)(Vtb + base
                + ((long)row << 11) + jbase + half * 64 + off);
        }
    };

    load_stage(0);

    #pragma unroll 1
    for (int jt = 0; jt < nr; ++jt) {
        __syncthreads();   // previous-round sk2/sv2 reads complete
        #pragma unroll
        for (int c = 0; c < 4; ++c) {
            const int cc   = c * 256 + tid;
            const int half = cc >> 9;
            const int row  = (cc >> 3) & 63;
            const int off  = (cc & 7) * 8;
            *(int4*)&sk2[half][row * LDP + off] = rK[c];
            *(int4*)&sv2[half][row * LDP + off] = rV[c];
        }
        __syncthreads();
        if (jt + 1 < nr) load_stage(jt + 1);   // retires under compute below

        #pragma unroll
        for (int half = 0; half < 2; ++half) {
            const int jt2 = 2 * jt + half;    // 64-key tile index
            if (jt2 > tB) continue;           // beyond heavy causal range
            const int jb2 = jt * 128 + half * 64;
            const short* skh = sk2[half];
            const short* svh = sv2[half];

            bf16x8 kf[4][2], vf[4][2];
            #pragma unroll
            for (int ct = 0; ct < 4; ++ct) {
                kf[ct][0] = *(const bf16x8*)&skh[(ct * 16 + l16) * LDP + quad * 8];
                kf[ct][1] = *(const bf16x8*)&skh[(ct * 16 + l16) * LDP + 32 + quad * 8];
                vf[ct][0] = *(const bf16x8*)&svh[(ct * 16 + l16) * LDP + quad * 8];
                vf[ct][1] = *(const bf16x8*)&svh[(ct * 16 + l16) * LDP + 32 + quad * 8];
            }

            if (jt2 <= tA)
                attn_tile(kf, vf, qfA, accA, mqA, lqA, spA[wave],
                          jb2, iqA, jt2 == tA);
            attn_tile(kf, vf, qfB, accB, mqB, lqB, spB[wave],
                      jb2, iqB, jt2 == tB);
        }
    }

    // epilogue: acc C-layout row=dim (ct*16+quad*4+reg), col=l16=query
    auto epi = [&](const f32x4 (&acc)[4], float lq, int iq) {
        const float inv = 1.f / lq;
        short* orow = ctx + (long)(b * SEQ + iq) * DATTN + h * HD;
        #pragma unroll
        for (int ct = 0; ct < 4; ++ct) {
            short4 o4;
            o4.x = f2bf(acc[ct][0] * inv);
            o4.y = f2bf(acc[ct][1] * inv);
            o4.z = f2bf(acc[ct][2] * inv);
            o4.w = f2bf(acc[ct][3] * inv);
            *(short4*)&orow[ct * 16 + quad * 4] = o4;
        }
    };
    epi(accA, lqA, iqA);
    epi(accB, lqB, iqB);
}

extern "C" void kernel_launch(void* const* d_in, const int* in_sizes, int n_in,
                              void* d_out, int out_size, void* d_ws, size_t ws_size,
                              hipStream_t stream) {
    const float* q  = (const float*)d_in[0];
    const float* k  = (const float*)d_in[1];
    const float* v  = (const float*)d_in[2];
    const float* Wq = (const float*)d_in[3];
    const float* Wk = (const float*)d_in[4];
    const float* Wv = (const float*)d_in[5];
    const float* Wo = (const float*)d_in[6];
    float* out = (float*)d_out;

    // workspace (bf16 shorts), 64 MB:
    // qb|kb|vb (4M shorts each) | wqb|wkb|wvb|wob (1M each) | Qb|Kb|Vtb|ctx (4M each)
    const long QKV = (long)MM * EMB;      // 4,194,304
    const long WSZ = (long)DATTN * EMB;   // 1,048,576
    short* basep = (short*)d_ws;
    short* qb  = basep;
    short* kb  = qb + QKV;
    short* vb  = kb + QKV;
    short* wqb = vb + QKV;
    short* wkb = wqb + WSZ;
    short* wvb = wkb + WSZ;
    short* wob = wvb + WSZ;
    short* Qb  = wob + WSZ;
    short* Kb  = Qb + QKV;
    short* Vtb = Kb + QKV;
    short* ctx = Vtb + QKV;

    // 1) fp32 -> bf16 pre-convert
    cvt_all<<<16384, 256, 0, stream>>>(q, k, v, Wq, Wk, Wv, Wo, qb);

    // 2) fused Q/K/V projection + RoPE
    gemm_proj_bf16<<<dim3(MM / 128, DATTN / 128, 3), 256, 0, stream>>>(
        qb, kb, vb, wqb, wkb, wvb, Qb, Kb, Vtb);

    // 3) flash attention (balanced dual-tile, 512 blocks = 2/CU co-resident)
    flash_attn_mfma<<<512, 256, 0, stream>>>(Qb, Kb, Vtb, ctx);

    // 4) output GEMM
    gemm_out_bf16<<<dim3(MM / 128, EMB / 128), 256, 0, stream>>>(ctx, wob, out);
}

// Round 2
// 230.038 us; speedup vs baseline: 1.1929x; 1.1929x over previous
//
#include <hip/hip_runtime.h>
#include <hip/hip_bf16.h>

// Problem constants (fixed shapes)
#define BATCH 2
#define SEQ   2048
#define EMB   1024
#define DATTN 1024
#define NH    16
#define HD    64
#define MM    (BATCH*SEQ)        // 4096 rows
#define SCALE 0.03125f           // 1/sqrt(1024), exact power of 2
#define MINIT -1.0e30f
#define ROPE_COEF 0.41524101186f // (2/64)*log2(10000)

using bf16x8 = __attribute__((ext_vector_type(8))) short;   // 8 bf16 (4 VGPRs)
using f32x4  = __attribute__((ext_vector_type(4))) float;   // MFMA C/D

__device__ inline short f2bf(float x) {
    __hip_bfloat16 b = __float2bfloat16(x);
    return *reinterpret_cast<short*>(&b);
}

// async global->LDS, 16 B per lane (wave-uniform LDS base). [m03/m97]
__device__ inline void gl_lds16(const short* g, short* l) {
    __builtin_amdgcn_global_load_lds(
        (const __attribute__((address_space(1))) unsigned int*)g,
        (__attribute__((address_space(3))) unsigned int*)l, 16, 0, 0);
}

// ---------------- fp32 -> bf16 pre-convert (q,k,v,Wq,Wk,Wv,Wo) ----------------
__global__ __launch_bounds__(256)
void cvt_all(const float* __restrict__ q, const float* __restrict__ k,
             const float* __restrict__ v,
             const float* __restrict__ Wq, const float* __restrict__ Wk,
             const float* __restrict__ Wv, const float* __restrict__ Wo,
             short* __restrict__ dst)
{
    const long QKV = (long)MM * EMB;      // 4,194,304
    const long WSZ = (long)DATTN * EMB;   // 1,048,576
    const long i = ((long)blockIdx.x * 256 + threadIdx.x) * 4;
    const float* s;
    long off;
    if (i < 3 * QKV) {
        const int seg = (int)(i / QKV);
        off = i - (long)seg * QKV;
        s = (seg == 0) ? q : (seg == 1) ? k : v;
    } else {
        const long j = i - 3 * QKV;
        const int seg = (int)(j / WSZ);
        off = j - (long)seg * WSZ;
        s = (seg == 0) ? Wq : (seg == 1) ? Wk : (seg == 2) ? Wv : Wo;
    }
    float4 x = *(const float4*)(s + off);
    short4 y;
    y.x = f2bf(x.x); y.y = f2bf(x.y); y.z = f2bf(x.z); y.w = f2bf(x.w);
    *(short4*)(dst + i) = y;
}

// ---------------- bf16 MFMA GEMM: 128x128 tile, BK=32, global_load_lds staging ----------------
__device__ inline void stage_tile(const short* g, short* lds, int wave, int lane) {
    #pragma unroll
    for (int qq = 0; qq < 2; ++qq) {
        const int r = wave * 32 + qq * 16 + (lane >> 2);
        gl_lds16(g + (long)r * EMB + (lane & 3) * 8, lds + (wave * 2 + qq) * 512);
    }
}

// Fused Q/K/V projection with RoPE fused into the epilogue for Q/K.
__global__ __launch_bounds__(256)
void gemm_proj_bf16(const short* __restrict__ qb, const short* __restrict__ kb,
                    const short* __restrict__ vb,
                    const short* __restrict__ wqb, const short* __restrict__ wkb,
                    const short* __restrict__ wvb,
                    short* __restrict__ Qb, short* __restrict__ Kb,
                    short* __restrict__ Vtb)
{
    const short* A; const short* B;
    if (blockIdx.z == 0)      { A = qb; B = wqb; }
    else if (blockIdx.z == 1) { A = kb; B = wkb; }
    else                      { A = vb; B = wvb; }

    __shared__ short sA[128 * 32];
    __shared__ short sB[128 * 32];

    const int tid  = threadIdx.x;
    const int wave = tid >> 6, lane = tid & 63;
    const int quad = lane >> 4, l16 = lane & 15;
    const int wm = (wave >> 1) * 64, wn = (wave & 1) * 64;
    const long m0 = (long)blockIdx.x * 128, n0 = (long)blockIdx.y * 128;

    f32x4 acc[4][4];
    #pragma unroll
    for (int i = 0; i < 4; ++i)
        #pragma unroll
        for (int j = 0; j < 4; ++j) acc[i][j] = (f32x4){0.f, 0.f, 0.f, 0.f};

    for (int kt = 0; kt < EMB; kt += 32) {
        __syncthreads();
        stage_tile(A + m0 * EMB + kt, sA, wave, lane);
        stage_tile(B + n0 * EMB + kt, sB, wave, lane);
        __syncthreads();

        bf16x8 af[4], bfr[4];
        #pragma unroll
        for (int rt = 0; rt < 4; ++rt)
            af[rt] = *(const bf16x8*)&sA[(wm + rt * 16 + l16) * 32 + quad * 8];
        #pragma unroll
        for (int ct = 0; ct < 4; ++ct)
            bfr[ct] = *(const bf16x8*)&sB[(wn + ct * 16 + l16) * 32 + quad * 8];
        #pragma unroll
        for (int rt = 0; rt < 4; ++rt)
            #pragma unroll
            for (int ct = 0; ct < 4; ++ct)
                acc[rt][ct] = __builtin_amdgcn_mfma_f32_16x16x32_bf16(
                    af[rt], bfr[ct], acc[rt][ct], 0, 0, 0);
    }

    if (blockIdx.z < 2) {
        // Q/K: fused RoPE (pair lives in adjacent l16 lanes -> shfl_xor(.,1))
        short* C = (blockIdx.z == 0) ? Qb : Kb;
        const float scl = (blockIdx.z == 0) ? SCALE : 1.0f;
        const int odd = l16 & 1;
        #pragma unroll
        for (int ct = 0; ct < 4; ++ct) {
            const long col = n0 + wn + ct * 16 + l16;
            const int hh = (int)(col >> 6), dd = (int)(col & (HD - 1));
            const float invf = exp2f(-ROPE_COEF * (float)(dd >> 1));
            #pragma unroll
            for (int rt = 0; rt < 4; ++rt) {
                #pragma unroll
                for (int reg = 0; reg < 4; ++reg) {
                    const long row = m0 + wm + rt * 16 + quad * 4 + reg;
                    const int bb = (int)(row >> 11), ss = (int)(row & (SEQ - 1));
                    const float val = acc[rt][ct][reg];
                    const float prt = __shfl_xor(val, 1, 64);
                    float sn, cs;
                    __sincosf((float)ss * invf, &sn, &cs);
                    const float o = odd ? (prt * sn + val * cs)
                                        : (val * cs - prt * sn);
                    C[(((long)(bb * NH + hh)) << 17) + ((long)ss << 6) + dd] =
                        f2bf(o * scl);
                }
            }
        }
    } else {
        // V transposed: Vt[((b*NH+h)*HD + d)*SEQ + s]
        #pragma unroll
        for (int rt = 0; rt < 4; ++rt) {
            #pragma unroll
            for (int ct = 0; ct < 4; ++ct) {
                const long row0 = m0 + wm + rt * 16 + quad * 4;
                const long col  = n0 + wn + ct * 16 + l16;
                const int bb = (int)(row0 >> 11), ss = (int)(row0 & (SEQ - 1));
                const int hh = (int)(col >> 6),   dd = (int)(col & (HD - 1));
                short4 s4;
                s4.x = f2bf(acc[rt][ct][0]); s4.y = f2bf(acc[rt][ct][1]);
                s4.z = f2bf(acc[rt][ct][2]); s4.w = f2bf(acc[rt][ct][3]);
                *(short4*)&Vtb[(((long)(bb * NH + hh)) << 17) + ((long)dd << 11) + ss] = s4;
            }
        }
    }
}

// Output GEMM: out = ctx(bf16) @ Wo^T(bf16), out fp32 [4096,1024]
__global__ __launch_bounds__(256)
void gemm_out_bf16(const short* __restrict__ Ab, const short* __restrict__ Bb,
                   float* __restrict__ C)
{
    __shared__ short sA[128 * 32];
    __shared__ short sB[128 * 32];

    const int tid  = threadIdx.x;
    const int wave = tid >> 6, lane = tid & 63;
    const int quad = lane >> 4, l16 = lane & 15;
    const int wm = (wave >> 1) * 64, wn = (wave & 1) * 64;
    const long m0 = (long)blockIdx.x * 128, n0 = (long)blockIdx.y * 128;

    f32x4 acc[4][4];
    #pragma unroll
    for (int i = 0; i < 4; ++i)
        #pragma unroll
        for (int j = 0; j < 4; ++j) acc[i][j] = (f32x4){0.f, 0.f, 0.f, 0.f};

    for (int kt = 0; kt < DATTN; kt += 32) {
        __syncthreads();
        stage_tile(Ab + m0 * DATTN + kt, sA, wave, lane);
        stage_tile(Bb + n0 * DATTN + kt, sB, wave, lane);
        __syncthreads();

        bf16x8 af[4], bfr[4];
        #pragma unroll
        for (int rt = 0; rt < 4; ++rt)
            af[rt] = *(const bf16x8*)&sA[(wm + rt * 16 + l16) * 32 + quad * 8];
        #pragma unroll
        for (int ct = 0; ct < 4; ++ct)
            bfr[ct] = *(const bf16x8*)&sB[(wn + ct * 16 + l16) * 32 + quad * 8];
        #pragma unroll
        for (int rt = 0; rt < 4; ++rt)
            #pragma unroll
            for (int ct = 0; ct < 4; ++ct)
                acc[rt][ct] = __builtin_amdgcn_mfma_f32_16x16x32_bf16(
                    af[rt], bfr[ct], acc[rt][ct], 0, 0, 0);
    }

    #pragma unroll
    for (int rt = 0; rt < 4; ++rt) {
        #pragma unroll
        for (int ct = 0; ct < 4; ++ct) {
            #pragma unroll
            for (int reg = 0; reg < 4; ++reg) {
                const long row = m0 + wm + rt * 16 + quad * 4 + reg;
                const long col = n0 + wn + ct * 16 + l16;
                C[row * EMB + col] = acc[rt][ct][reg];
            }
        }
    }
}

// ---------------- MFMA flash attention: TQ=128, dual 16-q groups per wave ----------------
// 512 blocks; block = (pair p, 128-query tile t). Each of the 4 waves owns 32
// CONTIGUOUS queries as two 16-q groups sharing every K/V fragment read (K frags
// feed 2 QK^T MFMAs, V frags feed 2 PV MFMAs) -> DS-ops per query ~halved vs the
// 68us TQ=64 version, which was LDS-pipe-bound (~40/68us on the per-CU DS pipe).
// Stage-rounds drop 8960 -> 4352. Balance: ids 0..255 carry t=8..15 (heavy,
// dispatched first), 256..511 carry t=0..7; id and id+256 share (residue,pair)
// and have t_h + t_l = 15 -> 17 round-units per CU under round-robin placement.
// XCD pinning: id&7 = residue; 4 pairs/XCD -> 2 MB K+V L2-resident (R12-verified).
// LDS 55.3 KB -> 2 blocks/CU (= the 512-block grid demand). No lambdas, no
// held staging regs (round-1 spill lesson: WRITE_SIZE is the canary).
#define LDP 72

__global__ __launch_bounds__(256, 2)
void flash_attn_mfma(const short* __restrict__ Qb,
                     const short* __restrict__ Kb,
                     const short* __restrict__ Vtb,
                     short* __restrict__ ctx)
{
    // id -> (xcd residue r, pair p, 128-query tile t)
    const int id  = blockIdx.x;           // 0..511
    const int hi  = id >> 8;              // 0 = heavy half, 1 = light half
    const int idx = id & 255;
    const int r   = idx & 7;              // XCD residue
    const int s5  = idx >> 3;             // 0..31
    const int pi  = s5 & 3;               // pair-within-residue
    const int ts8 = s5 >> 2;              // 0..7
    const int p   = r + 8 * pi;           // (b*NH+h) in [0,32)
    const int b   = p >> 4, h = p & 15;
    const int t   = hi ? ts8 : (15 - ts8);

    const int tid = threadIdx.x;
    const int wave = tid >> 6, lane = tid & 63;
    const int quad = lane >> 4, l16 = lane & 15;
    const int r0 = t * 128;

    __shared__ short sk2[2][64 * LDP];
    __shared__ short sv2[2][64 * LDP];
    __shared__ short sp[4][32 * LDP];     // per-wave: rows 0..15 = group0, 16..31 = group1

    const long base = ((long)(b * NH + h)) << 17;   // SEQ*HD = 2^17

    // two 16-query groups per wave (contiguous): iq1 = iq0 + 16
    const int iq0 = r0 + wave * 32 + l16;
    const int iq1 = iq0 + 16;
    // both groups of a wave share the same diagonal 64-key tile index
    const int dtile = 2 * t + (wave >> 1);

    bf16x8 qf0[2], qf1[2];
    #pragma unroll
    for (int tt = 0; tt < 2; ++tt) {
        qf0[tt] = *(const bf16x8*)(Qb + base + (long)iq0 * HD + tt * 32 + quad * 8);
        qf1[tt] = *(const bf16x8*)(Qb + base + (long)iq1 * HD + tt * 32 + quad * 8);
    }

    f32x4 acc0[4], acc1[4];
    #pragma unroll
    for (int ct = 0; ct < 4; ++ct) {
        acc0[ct] = (f32x4){0.f, 0.f, 0.f, 0.f};
        acc1[ct] = (f32x4){0.f, 0.f, 0.f, 0.f};
    }
    float m0 = MINIT, l0 = 0.f;
    float m1 = MINIT, l1 = 0.f;

    const int njt = t + 1;                // 128-key rounds

    #pragma unroll 1
    for (int jt = 0; jt < njt; ++jt) {
        const int jbase = jt * 128;

        __syncthreads();   // protect previous-iteration sk2/sv2 reads
        #pragma unroll
        for (int c = 0; c < 4; ++c) {
            int cc   = c * 256 + tid;         // 0..1023
            int half = cc >> 9;               // 0..1
            int row  = (cc >> 3) & 63;        // 0..63
            int off  = (cc & 7) * 8;          // 0..56
            int4 tK = *(const int4*)(Kb + base
                + (long)(jbase + half * 64 + row) * HD + off);
            *(int4*)&sk2[half][row * LDP + off] = tK;
            int4 tV = *(const int4*)(Vtb + base
                + ((long)row << 11) + jbase + half * 64 + off);
            *(int4*)&sv2[half][row * LDP + off] = tV;
        }
        __syncthreads();

        #pragma unroll
        for (int half = 0; half < 2; ++half) {
            const int jt2 = 2 * jt + half;    // 64-key tile index
            if (jt2 > dtile) continue;        // beyond this wave's causal range
            const int jb2 = jbase + half * 64;
            const short* skh = sk2[half];
            const short* svh = sv2[half];

            // S^T for both groups; K fragments loaded per-ct, shared by both
            // (C-layout: col=l16=query, row=quad*4+reg=key)
            f32x4 s0[4], s1[4];
            #pragma unroll
            for (int ct = 0; ct < 4; ++ct) {
                bf16x8 k0 = *(const bf16x8*)&skh[(ct * 16 + l16) * LDP + quad * 8];
                bf16x8 k1 = *(const bf16x8*)&skh[(ct * 16 + l16) * LDP + 32 + quad * 8];
                f32x4 z0 = (f32x4){0.f, 0.f, 0.f, 0.f};
                z0 = __builtin_amdgcn_mfma_f32_16x16x32_bf16(k0, qf0[0], z0, 0, 0, 0);
                z0 = __builtin_amdgcn_mfma_f32_16x16x32_bf16(k1, qf0[1], z0, 0, 0, 0);
                s0[ct] = z0;
                f32x4 z1 = (f32x4){0.f, 0.f, 0.f, 0.f};
                z1 = __builtin_amdgcn_mfma_f32_16x16x32_bf16(k0, qf1[0], z1, 0, 0, 0);
                z1 = __builtin_amdgcn_mfma_f32_16x16x32_bf16(k1, qf1[1], z1, 0, 0, 0);
                s1[ct] = z1;
            }

            if (jt2 == dtile) {   // diagonal tile: causal mask per group
                #pragma unroll
                for (int ct = 0; ct < 4; ++ct)
                    #pragma unroll
                    for (int rr = 0; rr < 4; ++rr) {
                        const int j = jb2 + ct * 16 + quad * 4 + rr;
                        if (!((j < iq0) || (iq0 == 0 && j == 0)))
                            s0[ct][rr] = -INFINITY;
                        if (!(j < iq1))               // iq1 >= 16, no (0,0) case
                            s1[ct][rr] = -INFINITY;
                    }
            }

            // online softmax, group 0
            float mx0 = MINIT;
            #pragma unroll
            for (int ct = 0; ct < 4; ++ct)
                #pragma unroll
                for (int rr = 0; rr < 4; ++rr) mx0 = fmaxf(mx0, s0[ct][rr]);
            mx0 = fmaxf(mx0, __shfl_xor(mx0, 16, 64));
            mx0 = fmaxf(mx0, __shfl_xor(mx0, 32, 64));
            const float mn0 = fmaxf(m0, mx0);
            const float a0 = __expf(m0 - mn0);
            m0 = mn0;
            float ss0 = 0.f;
            #pragma unroll
            for (int ct = 0; ct < 4; ++ct)
                #pragma unroll
                for (int rr = 0; rr < 4; ++rr) {
                    const float e = __expf(s0[ct][rr] - mn0);
                    s0[ct][rr] = e;
                    ss0 += e;
                }
            ss0 += __shfl_xor(ss0, 16, 64);
            ss0 += __shfl_xor(ss0, 32, 64);
            l0 = l0 * a0 + ss0;

            // online softmax, group 1
            float mx1 = MINIT;
            #pragma unroll
            for (int ct = 0; ct < 4; ++ct)
                #pragma unroll
                for (int rr = 0; rr < 4; ++rr) mx1 = fmaxf(mx1, s1[ct][rr]);
            mx1 = fmaxf(mx1, __shfl_xor(mx1, 16, 64));
            mx1 = fmaxf(mx1, __shfl_xor(mx1, 32, 64));
            const float mn1 = fmaxf(m1, mx1);
            const float a1 = __expf(m1 - mn1);
            m1 = mn1;
            float ss1 = 0.f;
            #pragma unroll
            for (int ct = 0; ct < 4; ++ct)
                #pragma unroll
                for (int rr = 0; rr < 4; ++rr) {
                    const float e = __expf(s1[ct][rr] - mn1);
                    s1[ct][rr] = e;
                    ss1 += e;
                }
            ss1 += __shfl_xor(ss1, 16, 64);
            ss1 += __shfl_xor(ss1, 32, 64);
            l1 = l1 * a1 + ss1;

            // P0/P1 -> LDS (separate 16-row halves), rescale, combined PV
            short* pw0 = sp[wave];
            short* pw1 = sp[wave] + 16 * LDP;
            #pragma unroll
            for (int ct = 0; ct < 4; ++ct) {
                short4 p4;
                p4.x = f2bf(s0[ct][0]); p4.y = f2bf(s0[ct][1]);
                p4.z = f2bf(s0[ct][2]); p4.w = f2bf(s0[ct][3]);
                *(short4*)&pw0[l16 * LDP + ct * 16 + quad * 4] = p4;
                short4 q4;
                q4.x = f2bf(s1[ct][0]); q4.y = f2bf(s1[ct][1]);
                q4.z = f2bf(s1[ct][2]); q4.w = f2bf(s1[ct][3]);
                *(short4*)&pw1[l16 * LDP + ct * 16 + quad * 4] = q4;
            }

            #pragma unroll
            for (int ct = 0; ct < 4; ++ct)
                #pragma unroll
                for (int rr = 0; rr < 4; ++rr) {
                    acc0[ct][rr] *= a0;
                    acc1[ct][rr] *= a1;
                }

            bf16x8 pf00 = *(const bf16x8*)&pw0[l16 * LDP + quad * 8];
            bf16x8 pf01 = *(const bf16x8*)&pw0[l16 * LDP + 32 + quad * 8];
            bf16x8 pf10 = *(const bf16x8*)&pw1[l16 * LDP + quad * 8];
            bf16x8 pf11 = *(const bf16x8*)&pw1[l16 * LDP + 32 + quad * 8];

            // PV: V fragments loaded per-ct, shared by both groups
            #pragma unroll
            for (int ct = 0; ct < 4; ++ct) {
                bf16x8 v0 = *(const bf16x8*)&svh[(ct * 16 + l16) * LDP + quad * 8];
                bf16x8 v1 = *(const bf16x8*)&svh[(ct * 16 + l16) * LDP + 32 + quad * 8];
                acc0[ct] = __builtin_amdgcn_mfma_f32_16x16x32_bf16(
                    v0, pf00, acc0[ct], 0, 0, 0);
                acc0[ct] = __builtin_amdgcn_mfma_f32_16x16x32_bf16(
                    v1, pf01, acc0[ct], 0, 0, 0);
                acc1[ct] = __builtin_amdgcn_mfma_f32_16x16x32_bf16(
                    v0, pf10, acc1[ct], 0, 0, 0);
                acc1[ct] = __builtin_amdgcn_mfma_f32_16x16x32_bf16(
                    v1, pf11, acc1[ct], 0, 0, 0);
            }
        }
    }

    // epilogue: acc C-layout row=dim (ct*16+quad*4+reg), col=l16=query
    {
        const float inv0 = 1.f / l0;
        short* orow = ctx + (long)(b * SEQ + iq0) * DATTN + h * HD;
        #pragma unroll
        for (int ct = 0; ct < 4; ++ct) {
            short4 o4;
            o4.x = f2bf(acc0[ct][0] * inv0);
            o4.y = f2bf(acc0[ct][1] * inv0);
            o4.z = f2bf(acc0[ct][2] * inv0);
            o4.w = f2bf(acc0[ct][3] * inv0);
            *(short4*)&orow[ct * 16 + quad * 4] = o4;
        }
    }
    {
        const float inv1 = 1.f / l1;
        short* orow = ctx + (long)(b * SEQ + iq1) * DATTN + h * HD;
        #pragma unroll
        for (int ct = 0; ct < 4; ++ct) {
            short4 o4;
            o4.x = f2bf(acc1[ct][0] * inv1);
            o4.y = f2bf(acc1[ct][1] * inv1);
            o4.z = f2bf(acc1[ct][2] * inv1);
            o4.w = f2bf(acc1[ct][3] * inv1);
            *(short4*)&orow[ct * 16 + quad * 4] = o4;
        }
    }
}

extern "C" void kernel_launch(void* const* d_in, const int* in_sizes, int n_in,
                              void* d_out, int out_size, void* d_ws, size_t ws_size,
                              hipStream_t stream) {
    const float* q  = (const float*)d_in[0];
    const float* k  = (const float*)d_in[1];
    const float* v  = (const float*)d_in[2];
    const float* Wq = (const float*)d_in[3];
    const float* Wk = (const float*)d_in[4];
    const float* Wv = (const float*)d_in[5];
    const float* Wo = (const float*)d_in[6];
    float* out = (float*)d_out;

    // workspace (bf16 shorts), 64 MB:
    // qb|kb|vb (4M shorts each) | wqb|wkb|wvb|wob (1M each) | Qb|Kb|Vtb|ctx (4M each)
    const long QKV = (long)MM * EMB;      // 4,194,304
    const long WSZ = (long)DATTN * EMB;   // 1,048,576
    short* basep = (short*)d_ws;
    short* qb  = basep;
    short* kb  = qb + QKV;
    short* vb  = kb + QKV;
    short* wqb = vb + QKV;
    short* wkb = wqb + WSZ;
    short* wvb = wkb + WSZ;
    short* wob = wvb + WSZ;
    short* Qb  = wob + WSZ;
    short* Kb  = Qb + QKV;
    short* Vtb = Kb + QKV;
    short* ctx = Vtb + QKV;

    // 1) fp32 -> bf16 pre-convert
    cvt_all<<<16384, 256, 0, stream>>>(q, k, v, Wq, Wk, Wv, Wo, qb);

    // 2) fused Q/K/V projection + RoPE
    gemm_proj_bf16<<<dim3(MM / 128, DATTN / 128, 3), 256, 0, stream>>>(
        qb, kb, vb, wqb, wkb, wvb, Qb, Kb, Vtb);

    // 3) flash attention (TQ=128 dual-group, 512 blocks, heavy-first balanced)
    flash_attn_mfma<<<512, 256, 0, stream>>>(Qb, Kb, Vtb, ctx);

    // 4) output GEMM
    gemm_out_bf16<<<dim3(MM / 128, EMB / 128), 256, 0, stream>>>(ctx, wob, out);
}

// Round 3
// 222.397 us; speedup vs baseline: 1.2339x; 1.0344x over previous
//
#include <hip/hip_runtime.h>
#include <hip/hip_bf16.h>

// Problem constants (fixed shapes)
#define BATCH 2
#define SEQ   2048
#define EMB   1024
#define DATTN 1024
#define NH    16
#define HD    64
#define MM    (BATCH*SEQ)        // 4096 rows
#define SCALE 0.03125f           // 1/sqrt(1024), exact power of 2
#define MINIT -1.0e30f
#define ROPE_COEF 0.41524101186f // (2/64)*log2(10000)

using bf16x8 = __attribute__((ext_vector_type(8))) short;   // 8 bf16 (4 VGPRs)
using f32x4  = __attribute__((ext_vector_type(4))) float;   // MFMA C/D

__device__ inline short f2bf(float x) {
    __hip_bfloat16 b = __float2bfloat16(x);
    return *reinterpret_cast<short*>(&b);
}

// async global->LDS, 16 B per lane (wave-uniform LDS base). [m03/m97]
__device__ inline void gl_lds16(const short* g, short* l) {
    __builtin_amdgcn_global_load_lds(
        (const __attribute__((address_space(1))) unsigned int*)g,
        (__attribute__((address_space(3))) unsigned int*)l, 16, 0, 0);
}

// ---------------- fp32 -> bf16 pre-convert (q,k,v,Wq,Wk,Wv,Wo) ----------------
__global__ __launch_bounds__(256)
void cvt_all(const float* __restrict__ q, const float* __restrict__ k,
             const float* __restrict__ v,
             const float* __restrict__ Wq, const float* __restrict__ Wk,
             const float* __restrict__ Wv, const float* __restrict__ Wo,
             short* __restrict__ dst)
{
    const long QKV = (long)MM * EMB;      // 4,194,304
    const long WSZ = (long)DATTN * EMB;   // 1,048,576
    const long i = ((long)blockIdx.x * 256 + threadIdx.x) * 4;
    const float* s;
    long off;
    if (i < 3 * QKV) {
        const int seg = (int)(i / QKV);
        off = i - (long)seg * QKV;
        s = (seg == 0) ? q : (seg == 1) ? k : v;
    } else {
        const long j = i - 3 * QKV;
        const int seg = (int)(j / WSZ);
        off = j - (long)seg * WSZ;
        s = (seg == 0) ? Wq : (seg == 1) ? Wk : (seg == 2) ? Wv : Wo;
    }
    float4 x = *(const float4*)(s + off);
    short4 y;
    y.x = f2bf(x.x); y.y = f2bf(x.y); y.z = f2bf(x.z); y.w = f2bf(x.w);
    *(short4*)(dst + i) = y;
}

// ---------------- bf16 MFMA GEMM: 128x128 tile, BK=32, global_load_lds staging ----------------
__device__ inline void stage_tile(const short* g, short* lds, int wave, int lane) {
    #pragma unroll
    for (int qq = 0; qq < 2; ++qq) {
        const int r = wave * 32 + qq * 16 + (lane >> 2);
        gl_lds16(g + (long)r * EMB + (lane & 3) * 8, lds + (wave * 2 + qq) * 512);
    }
}

// Fused Q/K/V projection with RoPE fused into the epilogue for Q/K.
__global__ __launch_bounds__(256)
void gemm_proj_bf16(const short* __restrict__ qb, const short* __restrict__ kb,
                    const short* __restrict__ vb,
                    const short* __restrict__ wqb, const short* __restrict__ wkb,
                    const short* __restrict__ wvb,
                    short* __restrict__ Qb, short* __restrict__ Kb,
                    short* __restrict__ Vtb)
{
    const short* A; const short* B;
    if (blockIdx.z == 0)      { A = qb; B = wqb; }
    else if (blockIdx.z == 1) { A = kb; B = wkb; }
    else                      { A = vb; B = wvb; }

    __shared__ short sA[128 * 32];
    __shared__ short sB[128 * 32];

    const int tid  = threadIdx.x;
    const int wave = tid >> 6, lane = tid & 63;
    const int quad = lane >> 4, l16 = lane & 15;
    const int wm = (wave >> 1) * 64, wn = (wave & 1) * 64;
    const long m0 = (long)blockIdx.x * 128, n0 = (long)blockIdx.y * 128;

    f32x4 acc[4][4];
    #pragma unroll
    for (int i = 0; i < 4; ++i)
        #pragma unroll
        for (int j = 0; j < 4; ++j) acc[i][j] = (f32x4){0.f, 0.f, 0.f, 0.f};

    for (int kt = 0; kt < EMB; kt += 32) {
        __syncthreads();
        stage_tile(A + m0 * EMB + kt, sA, wave, lane);
        stage_tile(B + n0 * EMB + kt, sB, wave, lane);
        __syncthreads();

        bf16x8 af[4], bfr[4];
        #pragma unroll
        for (int rt = 0; rt < 4; ++rt)
            af[rt] = *(const bf16x8*)&sA[(wm + rt * 16 + l16) * 32 + quad * 8];
        #pragma unroll
        for (int ct = 0; ct < 4; ++ct)
            bfr[ct] = *(const bf16x8*)&sB[(wn + ct * 16 + l16) * 32 + quad * 8];
        #pragma unroll
        for (int rt = 0; rt < 4; ++rt)
            #pragma unroll
            for (int ct = 0; ct < 4; ++ct)
                acc[rt][ct] = __builtin_amdgcn_mfma_f32_16x16x32_bf16(
                    af[rt], bfr[ct], acc[rt][ct], 0, 0, 0);
    }

    if (blockIdx.z < 2) {
        // Q/K: fused RoPE (pair lives in adjacent l16 lanes -> shfl_xor(.,1))
        short* C = (blockIdx.z == 0) ? Qb : Kb;
        const float scl = (blockIdx.z == 0) ? SCALE : 1.0f;
        const int odd = l16 & 1;
        #pragma unroll
        for (int ct = 0; ct < 4; ++ct) {
            const long col = n0 + wn + ct * 16 + l16;
            const int hh = (int)(col >> 6), dd = (int)(col & (HD - 1));
            const float invf = exp2f(-ROPE_COEF * (float)(dd >> 1));
            #pragma unroll
            for (int rt = 0; rt < 4; ++rt) {
                #pragma unroll
                for (int reg = 0; reg < 4; ++reg) {
                    const long row = m0 + wm + rt * 16 + quad * 4 + reg;
                    const int bb = (int)(row >> 11), ss = (int)(row & (SEQ - 1));
                    const float val = acc[rt][ct][reg];
                    const float prt = __shfl_xor(val, 1, 64);
                    float sn, cs;
                    __sincosf((float)ss * invf, &sn, &cs);
                    const float o = odd ? (prt * sn + val * cs)
                                        : (val * cs - prt * sn);
                    C[(((long)(bb * NH + hh)) << 17) + ((long)ss << 6) + dd] =
                        f2bf(o * scl);
                }
            }
        }
    } else {
        // V transposed: Vt[((b*NH+h)*HD + d)*SEQ + s]
        #pragma unroll
        for (int rt = 0; rt < 4; ++rt) {
            #pragma unroll
            for (int ct = 0; ct < 4; ++ct) {
                const long row0 = m0 + wm + rt * 16 + quad * 4;
                const long col  = n0 + wn + ct * 16 + l16;
                const int bb = (int)(row0 >> 11), ss = (int)(row0 & (SEQ - 1));
                const int hh = (int)(col >> 6),   dd = (int)(col & (HD - 1));
                short4 s4;
                s4.x = f2bf(acc[rt][ct][0]); s4.y = f2bf(acc[rt][ct][1]);
                s4.z = f2bf(acc[rt][ct][2]); s4.w = f2bf(acc[rt][ct][3]);
                *(short4*)&Vtb[(((long)(bb * NH + hh)) << 17) + ((long)dd << 11) + ss] = s4;
            }
        }
    }
}

// Output GEMM: out = ctx(bf16) @ Wo^T(bf16), out fp32 [4096,1024]
// 128x64 tiles -> 512 blocks = 2 blocks/CU (was 256 = 1/CU: barrier drain fully
// exposed, ~280 TF). Per wave 64x32 output, 8 MFMA + 6 ds_read_b128 per K-step.
__global__ __launch_bounds__(256)
void gemm_out_bf16(const short* __restrict__ Ab, const short* __restrict__ Bb,
                   float* __restrict__ C)
{
    __shared__ short sA[128 * 32];
    __shared__ short sB[64 * 32];

    const int tid  = threadIdx.x;
    const int wave = tid >> 6, lane = tid & 63;
    const int quad = lane >> 4, l16 = lane & 15;
    const int wm = (wave >> 1) * 64, wn = (wave & 1) * 32;
    const long m0 = (long)blockIdx.x * 128, n0 = (long)blockIdx.y * 64;

    f32x4 acc[4][2];
    #pragma unroll
    for (int i = 0; i < 4; ++i)
        #pragma unroll
        for (int j = 0; j < 2; ++j) acc[i][j] = (f32x4){0.f, 0.f, 0.f, 0.f};

    for (int kt = 0; kt < DATTN; kt += 32) {
        __syncthreads();
        stage_tile(Ab + m0 * DATTN + kt, sA, wave, lane);
        // B tile 64x32: one gl_lds16 per thread (rows wave*16.., chunk lane&3)
        gl_lds16(Bb + n0 * DATTN + kt
                     + (long)(wave * 16 + (lane >> 2)) * DATTN + (lane & 3) * 8,
                 sB + wave * 512);
        __syncthreads();

        bf16x8 af[4], bfr[2];
        #pragma unroll
        for (int rt = 0; rt < 4; ++rt)
            af[rt] = *(const bf16x8*)&sA[(wm + rt * 16 + l16) * 32 + quad * 8];
        #pragma unroll
        for (int ct = 0; ct < 2; ++ct)
            bfr[ct] = *(const bf16x8*)&sB[(wn + ct * 16 + l16) * 32 + quad * 8];
        #pragma unroll
        for (int rt = 0; rt < 4; ++rt)
            #pragma unroll
            for (int ct = 0; ct < 2; ++ct)
                acc[rt][ct] = __builtin_amdgcn_mfma_f32_16x16x32_bf16(
                    af[rt], bfr[ct], acc[rt][ct], 0, 0, 0);
    }

    #pragma unroll
    for (int rt = 0; rt < 4; ++rt) {
        #pragma unroll
        for (int ct = 0; ct < 2; ++ct) {
            #pragma unroll
            for (int reg = 0; reg < 4; ++reg) {
                const long row = m0 + wm + rt * 16 + quad * 4 + reg;
                const long col = n0 + wn + ct * 16 + l16;
                C[row * EMB + col] = acc[rt][ct][reg];
            }
        }
    }
}

// ---------------- MFMA flash attention: TQ=128, gl_lds-staged K/V, swizzled ----------------
// 512 blocks; block = (pair p, 128-query tile t); 4 waves x two 16-q groups sharing
// all K/V fragment reads. K/V staged via global_load_lds (16B/lane, linear LDS dest,
// PRE-SWIZZLED global source chunk off^(row&7); reads apply the same XOR — rule-21
// both-sides pattern). Removes 8 ds_write_b128 + staging VALU per thread/round vs R2.
// Balance: ids 0..255 carry t=8..15 (heavy first), 256..511 t=0..7 (t_h+t_l=15).
// XCD pinning: id&7 = residue; 4 pairs/XCD -> K/V L2-resident. LDS 50 KB.
// T5: s_setprio(1) around MFMA clusters (2 independent blocks/CU -> role diversity).
#define KLD 64   // K/V LDS row stride (shorts) — linear, swizzle in chunk index
#define PLD 72   // P buffer row stride (shorts)

__global__ __launch_bounds__(256, 2)
void flash_attn_mfma(const short* __restrict__ Qb,
                     const short* __restrict__ Kb,
                     const short* __restrict__ Vtb,
                     short* __restrict__ ctx)
{
    // id -> (xcd residue r, pair p, 128-query tile t)
    const int id  = blockIdx.x;           // 0..511
    const int hi  = id >> 8;              // 0 = heavy half, 1 = light half
    const int idx = id & 255;
    const int r   = idx & 7;              // XCD residue
    const int s5  = idx >> 3;             // 0..31
    const int pi  = s5 & 3;               // pair-within-residue
    const int ts8 = s5 >> 2;              // 0..7
    const int p   = r + 8 * pi;           // (b*NH+h) in [0,32)
    const int b   = p >> 4, h = p & 15;
    const int t   = hi ? ts8 : (15 - ts8);

    const int tid = threadIdx.x;
    const int wave = tid >> 6, lane = tid & 63;
    const int quad = lane >> 4, l16 = lane & 15;
    const int r0 = t * 128;

    __shared__ short sk[2 * 64 * KLD];    // [half][row][chunk] linear (16 KB)
    __shared__ short sv[2 * 64 * KLD];    // (16 KB)
    __shared__ short sp[4][32 * PLD];     // per-wave P: rows 0..15 g0, 16..31 g1 (18 KB)

    const long base = ((long)(b * NH + h)) << 17;   // SEQ*HD = 2^17

    // two 16-query groups per wave (contiguous): iq1 = iq0 + 16
    const int iq0 = r0 + wave * 32 + l16;
    const int iq1 = iq0 + 16;
    const int dtile = 2 * t + (wave >> 1);   // this wave's diagonal 64-key tile
    const int rsw = l16 & 7;                 // read-side swizzle (row&7 == l16&7)

    bf16x8 qf0[2], qf1[2];
    #pragma unroll
    for (int tt = 0; tt < 2; ++tt) {
        qf0[tt] = *(const bf16x8*)(Qb + base + (long)iq0 * HD + tt * 32 + quad * 8);
        qf1[tt] = *(const bf16x8*)(Qb + base + (long)iq1 * HD + tt * 32 + quad * 8);
    }

    f32x4 acc0[4], acc1[4];
    #pragma unroll
    for (int ct = 0; ct < 4; ++ct) {
        acc0[ct] = (f32x4){0.f, 0.f, 0.f, 0.f};
        acc1[ct] = (f32x4){0.f, 0.f, 0.f, 0.f};
    }
    float m0 = MINIT, l0 = 0.f;
    float m1 = MINIT, l1 = 0.f;

    const int njt = t + 1;                // 128-key rounds

    #pragma unroll 1
    for (int jt = 0; jt < njt; ++jt) {
        const int jbase = jt * 128;

        __syncthreads();   // previous-round sk/sv reads complete
        #pragma unroll
        for (int c = 0; c < 4; ++c) {
            const int cc   = c * 256 + tid;        // 16B-chunk index 0..1023
            const int half = cc >> 9;
            const int row  = (cc >> 3) & 63;
            const int sch  = (cc & 7) ^ (row & 7); // pre-swizzled source chunk
            // LDS dest: wave-uniform base; HW adds lane*16B -> chunk cc linear
            gl_lds16(Kb + base + (long)(jbase + half * 64 + row) * HD + sch * 8,
                     sk + ((c * 256 + wave * 64) << 3));
            gl_lds16(Vtb + base + ((long)row << 11) + jbase + half * 64 + sch * 8,
                     sv + ((c * 256 + wave * 64) << 3));
        }
        __syncthreads();   // vmcnt(0) drain -> staged data visible

        #pragma unroll
        for (int half = 0; half < 2; ++half) {
            const int jt2 = 2 * jt + half;    // 64-key tile index
            if (jt2 > dtile) continue;        // beyond this wave's causal range
            const int jb2 = jbase + half * 64;
            const short* skh = sk + half * 64 * KLD;
            const short* svh = sv + half * 64 * KLD;

            // S^T for both groups; K fragments per-ct, shared by both groups.
            // Read swizzle: G[row][slot] lives at LDS chunk slot^(row&7).
            f32x4 s0[4], s1[4];
            __builtin_amdgcn_s_setprio(1);
            #pragma unroll
            for (int ct = 0; ct < 4; ++ct) {
                const int rr16 = (ct * 16 + l16) * KLD;
                bf16x8 k0 = *(const bf16x8*)&skh[rr16 + ((quad ^ rsw) << 3)];
                bf16x8 k1 = *(const bf16x8*)&skh[rr16 + (((4 + quad) ^ rsw) << 3)];
                f32x4 z0 = (f32x4){0.f, 0.f, 0.f, 0.f};
                z0 = __builtin_amdgcn_mfma_f32_16x16x32_bf16(k0, qf0[0], z0, 0, 0, 0);
                z0 = __builtin_amdgcn_mfma_f32_16x16x32_bf16(k1, qf0[1], z0, 0, 0, 0);
                s0[ct] = z0;
                f32x4 z1 = (f32x4){0.f, 0.f, 0.f, 0.f};
                z1 = __builtin_amdgcn_mfma_f32_16x16x32_bf16(k0, qf1[0], z1, 0, 0, 0);
                z1 = __builtin_amdgcn_mfma_f32_16x16x32_bf16(k1, qf1[1], z1, 0, 0, 0);
                s1[ct] = z1;
            }
            __builtin_amdgcn_s_setprio(0);

            if (jt2 == dtile) {   // diagonal tile: causal mask per group
                #pragma unroll
                for (int ct = 0; ct < 4; ++ct)
                    #pragma unroll
                    for (int rr = 0; rr < 4; ++rr) {
                        const int j = jb2 + ct * 16 + quad * 4 + rr;
                        if (!((j < iq0) || (iq0 == 0 && j == 0)))
                            s0[ct][rr] = -INFINITY;
                        if (!(j < iq1))               // iq1 >= 16, no (0,0) case
                            s1[ct][rr] = -INFINITY;
                    }
            }

            // online softmax, group 0
            float mx0 = MINIT;
            #pragma unroll
            for (int ct = 0; ct < 4; ++ct)
                #pragma unroll
                for (int rr = 0; rr < 4; ++rr) mx0 = fmaxf(mx0, s0[ct][rr]);
            mx0 = fmaxf(mx0, __shfl_xor(mx0, 16, 64));
            mx0 = fmaxf(mx0, __shfl_xor(mx0, 32, 64));
            const float mn0 = fmaxf(m0, mx0);
            const float a0 = __expf(m0 - mn0);
            m0 = mn0;
            float ss0 = 0.f;
            #pragma unroll
            for (int ct = 0; ct < 4; ++ct)
                #pragma unroll
                for (int rr = 0; rr < 4; ++rr) {
                    const float e = __expf(s0[ct][rr] - mn0);
                    s0[ct][rr] = e;
                    ss0 += e;
                }
            ss0 += __shfl_xor(ss0, 16, 64);
            ss0 += __shfl_xor(ss0, 32, 64);
            l0 = l0 * a0 + ss0;

            // online softmax, group 1
            float mx1 = MINIT;
            #pragma unroll
            for (int ct = 0; ct < 4; ++ct)
                #pragma unroll
                for (int rr = 0; rr < 4; ++rr) mx1 = fmaxf(mx1, s1[ct][rr]);
            mx1 = fmaxf(mx1, __shfl_xor(mx1, 16, 64));
            mx1 = fmaxf(mx1, __shfl_xor(mx1, 32, 64));
            const float mn1 = fmaxf(m1, mx1);
            const float a1 = __expf(m1 - mn1);
            m1 = mn1;
            float ss1 = 0.f;
            #pragma unroll
            for (int ct = 0; ct < 4; ++ct)
                #pragma unroll
                for (int rr = 0; rr < 4; ++rr) {
                    const float e = __expf(s1[ct][rr] - mn1);
                    s1[ct][rr] = e;
                    ss1 += e;
                }
            ss1 += __shfl_xor(ss1, 16, 64);
            ss1 += __shfl_xor(ss1, 32, 64);
            l1 = l1 * a1 + ss1;

            // P0/P1 -> LDS (separate 16-row halves), rescale, combined PV
            short* pw0 = sp[wave];
            short* pw1 = sp[wave] + 16 * PLD;
            #pragma unroll
            for (int ct = 0; ct < 4; ++ct) {
                short4 p4;
                p4.x = f2bf(s0[ct][0]); p4.y = f2bf(s0[ct][1]);
                p4.z = f2bf(s0[ct][2]); p4.w = f2bf(s0[ct][3]);
                *(short4*)&pw0[l16 * PLD + ct * 16 + quad * 4] = p4;
                short4 q4;
                q4.x = f2bf(s1[ct][0]); q4.y = f2bf(s1[ct][1]);
                q4.z = f2bf(s1[ct][2]); q4.w = f2bf(s1[ct][3]);
                *(short4*)&pw1[l16 * PLD + ct * 16 + quad * 4] = q4;
            }

            #pragma unroll
            for (int ct = 0; ct < 4; ++ct)
                #pragma unroll
                for (int rr = 0; rr < 4; ++rr) {
                    acc0[ct][rr] *= a0;
                    acc1[ct][rr] *= a1;
                }

            bf16x8 pf00 = *(const bf16x8*)&pw0[l16 * PLD + quad * 8];
            bf16x8 pf01 = *(const bf16x8*)&pw0[l16 * PLD + 32 + quad * 8];
            bf16x8 pf10 = *(const bf16x8*)&pw1[l16 * PLD + quad * 8];
            bf16x8 pf11 = *(const bf16x8*)&pw1[l16 * PLD + 32 + quad * 8];

            // PV: V fragments per-ct, shared by both groups (same swizzled reads)
            __builtin_amdgcn_s_setprio(1);
            #pragma unroll
            for (int ct = 0; ct < 4; ++ct) {
                const int rr16 = (ct * 16 + l16) * KLD;
                bf16x8 v0 = *(const bf16x8*)&svh[rr16 + ((quad ^ rsw) << 3)];
                bf16x8 v1 = *(const bf16x8*)&svh[rr16 + (((4 + quad) ^ rsw) << 3)];
                acc0[ct] = __builtin_amdgcn_mfma_f32_16x16x32_bf16(
                    v0, pf00, acc0[ct], 0, 0, 0);
                acc0[ct] = __builtin_amdgcn_mfma_f32_16x16x32_bf16(
                    v1, pf01, acc0[ct], 0, 0, 0);
                acc1[ct] = __builtin_amdgcn_mfma_f32_16x16x32_bf16(
                    v0, pf10, acc1[ct], 0, 0, 0);
                acc1[ct] = __builtin_amdgcn_mfma_f32_16x16x32_bf16(
                    v1, pf11, acc1[ct], 0, 0, 0);
            }
            __builtin_amdgcn_s_setprio(0);
        }
    }

    // epilogue: acc C-layout row=dim (ct*16+quad*4+reg), col=l16=query
    {
        const float inv0 = 1.f / l0;
        short* orow = ctx + (long)(b * SEQ + iq0) * DATTN + h * HD;
        #pragma unroll
        for (int ct = 0; ct < 4; ++ct) {
            short4 o4;
            o4.x = f2bf(acc0[ct][0] * inv0);
            o4.y = f2bf(acc0[ct][1] * inv0);
            o4.z = f2bf(acc0[ct][2] * inv0);
            o4.w = f2bf(acc0[ct][3] * inv0);
            *(short4*)&orow[ct * 16 + quad * 4] = o4;
        }
    }
    {
        const float inv1 = 1.f / l1;
        short* orow = ctx + (long)(b * SEQ + iq1) * DATTN + h * HD;
        #pragma unroll
        for (int ct = 0; ct < 4; ++ct) {
            short4 o4;
            o4.x = f2bf(acc1[ct][0] * inv1);
            o4.y = f2bf(acc1[ct][1] * inv1);
            o4.z = f2bf(acc1[ct][2] * inv1);
            o4.w = f2bf(acc1[ct][3] * inv1);
            *(short4*)&orow[ct * 16 + quad * 4] = o4;
        }
    }
}

extern "C" void kernel_launch(void* const* d_in, const int* in_sizes, int n_in,
                              void* d_out, int out_size, void* d_ws, size_t ws_size,
                              hipStream_t stream) {
    const float* q  = (const float*)d_in[0];
    const float* k  = (const float*)d_in[1];
    const float* v  = (const float*)d_in[2];
    const float* Wq = (const float*)d_in[3];
    const float* Wk = (const float*)d_in[4];
    const float* Wv = (const float*)d_in[5];
    const float* Wo = (const float*)d_in[6];
    float* out = (float*)d_out;

    // workspace (bf16 shorts), 64 MB:
    // qb|kb|vb (4M shorts each) | wqb|wkb|wvb|wob (1M each) | Qb|Kb|Vtb|ctx (4M each)
    const long QKV = (long)MM * EMB;      // 4,194,304
    const long WSZ = (long)DATTN * EMB;   // 1,048,576
    short* basep = (short*)d_ws;
    short* qb  = basep;
    short* kb  = qb + QKV;
    short* vb  = kb + QKV;
    short* wqb = vb + QKV;
    short* wkb = wqb + WSZ;
    short* wvb = wkb + WSZ;
    short* wob = wvb + WSZ;
    short* Qb  = wob + WSZ;
    short* Kb  = Qb + QKV;
    short* Vtb = Kb + QKV;
    short* ctx = Vtb + QKV;

    // 1) fp32 -> bf16 pre-convert
    cvt_all<<<16384, 256, 0, stream>>>(q, k, v, Wq, Wk, Wv, Wo, qb);

    // 2) fused Q/K/V projection + RoPE
    gemm_proj_bf16<<<dim3(MM / 128, DATTN / 128, 3), 256, 0, stream>>>(
        qb, kb, vb, wqb, wkb, wvb, Qb, Kb, Vtb);

    // 3) flash attention (TQ=128 dual-group, gl_lds-staged, 512 blocks)
    flash_attn_mfma<<<512, 256, 0, stream>>>(Qb, Kb, Vtb, ctx);

    // 4) output GEMM (128x64 tiles -> 512 blocks = 2/CU)
    gemm_out_bf16<<<dim3(MM / 128, EMB / 64), 256, 0, stream>>>(ctx, wob, out);
}

// Round 4
// 214.445 us; speedup vs baseline: 1.2797x; 1.0371x over previous
//
#include <hip/hip_runtime.h>
#include <hip/hip_bf16.h>

// Problem constants (fixed shapes)
#define BATCH 2
#define SEQ   2048
#define EMB   1024
#define DATTN 1024
#define NH    16
#define HD    64
#define MM    (BATCH*SEQ)        // 4096 rows
#define SCALE 0.03125f           // 1/sqrt(1024), exact power of 2
#define MINIT -1.0e30f
#define ROPE_COEF 0.41524101186f // (2/64)*log2(10000)

using bf16x8 = __attribute__((ext_vector_type(8))) short;   // 8 bf16 (4 VGPRs)
using f32x4  = __attribute__((ext_vector_type(4))) float;   // MFMA C/D

__device__ inline short f2bf(float x) {
    __hip_bfloat16 b = __float2bfloat16(x);
    return *reinterpret_cast<short*>(&b);
}

// async global->LDS, 16 B per lane (wave-uniform LDS base). [m03/m97]
__device__ inline void gl_lds16(const short* g, short* l) {
    __builtin_amdgcn_global_load_lds(
        (const __attribute__((address_space(1))) unsigned int*)g,
        (__attribute__((address_space(3))) unsigned int*)l, 16, 0, 0);
}

// ---------------- fp32 -> bf16 pre-convert (q,k,v,Wq,Wk,Wv,Wo) ----------------
__global__ __launch_bounds__(256)
void cvt_all(const float* __restrict__ q, const float* __restrict__ k,
             const float* __restrict__ v,
             const float* __restrict__ Wq, const float* __restrict__ Wk,
             const float* __restrict__ Wv, const float* __restrict__ Wo,
             short* __restrict__ dst)
{
    const long QKV = (long)MM * EMB;      // 4,194,304
    const long WSZ = (long)DATTN * EMB;   // 1,048,576
    const long i = ((long)blockIdx.x * 256 + threadIdx.x) * 4;
    const float* s;
    long off;
    if (i < 3 * QKV) {
        const int seg = (int)(i / QKV);
        off = i - (long)seg * QKV;
        s = (seg == 0) ? q : (seg == 1) ? k : v;
    } else {
        const long j = i - 3 * QKV;
        const int seg = (int)(j / WSZ);
        off = j - (long)seg * WSZ;
        s = (seg == 0) ? Wq : (seg == 1) ? Wk : (seg == 2) ? Wv : Wo;
    }
    float4 x = *(const float4*)(s + off);
    short4 y;
    y.x = f2bf(x.x); y.y = f2bf(x.y); y.z = f2bf(x.z); y.w = f2bf(x.w);
    *(short4*)(dst + i) = y;
}

// ---------------- staging helpers ----------------
// BK=32 staging (gemm_out): 128x32 tile, linear LDS.
__device__ inline void stage_tile(const short* g, short* lds, int wave, int lane) {
    #pragma unroll
    for (int qq = 0; qq < 2; ++qq) {
        const int r = wave * 32 + qq * 16 + (lane >> 2);
        gl_lds16(g + (long)r * EMB + (lane & 3) * 8, lds + (wave * 2 + qq) * 512);
    }
}

// BK=64 staging (proj): 128x64 tile, linear LDS dest, XOR pre-swizzled source
// chunk slot^(row&7) over the 8 chunks/row (rule-21 both-sides pattern; the
// fragment reads apply the same XOR -> 2-way banked = free).
__device__ inline void stage_tile64(const short* g, short* lds, int tid) {
    #pragma unroll
    for (int c = 0; c < 4; ++c) {
        const int cc   = c * 256 + tid;       // 16B-chunk index 0..1023
        const int row  = cc >> 3;             // 0..127
        const int slot = cc & 7;              // 0..7
        const int ssl  = slot ^ (row & 7);    // pre-swizzled source chunk
        gl_lds16(g + (long)row * EMB + ssl * 8, lds + ((cc & ~63) << 3));
    }
}

// ---------------- fused Q/K/V projection, BK=64, RoPE epilogue ----------------
// 128x128 tile, 16 K-steps (half the barrier drains of BK=32 at K=1024).
// Q/K slices compute C^T (mfma(bfr,af): rows=dims in regs, cols=tokens in l16)
// so the rotary pair is IN-LANE (regs 0/1, 2/3): no shfl, 2 sincos per 4 elems,
// aligned short4 stores. V keeps original order (Vt needs tokens in regs).
__global__ __launch_bounds__(256)
void gemm_proj_bf16(const short* __restrict__ qb, const short* __restrict__ kb,
                    const short* __restrict__ vb,
                    const short* __restrict__ wqb, const short* __restrict__ wkb,
                    const short* __restrict__ wvb,
                    short* __restrict__ Qb, short* __restrict__ Kb,
                    short* __restrict__ Vtb)
{
    const short* A; const short* B;
    if (blockIdx.z == 0)      { A = qb; B = wqb; }
    else if (blockIdx.z == 1) { A = kb; B = wkb; }
    else                      { A = vb; B = wvb; }
    const bool isv = (blockIdx.z == 2);

    __shared__ short sA[128 * 64];   // 16 KB
    __shared__ short sB[128 * 64];   // 16 KB

    const int tid  = threadIdx.x;
    const int wave = tid >> 6, lane = tid & 63;
    const int quad = lane >> 4, l16 = lane & 15;
    const int wm = (wave >> 1) * 64, wn = (wave & 1) * 64;
    const long m0 = (long)blockIdx.x * 128, n0 = (long)blockIdx.y * 128;
    const int rsw = l16 & 7;         // read-side swizzle (row&7 == l16&7)

    f32x4 acc[4][4];
    #pragma unroll
    for (int i = 0; i < 4; ++i)
        #pragma unroll
        for (int j = 0; j < 4; ++j) acc[i][j] = (f32x4){0.f, 0.f, 0.f, 0.f};

    for (int kt = 0; kt < EMB; kt += 64) {
        __syncthreads();
        stage_tile64(A + m0 * EMB + kt, sA, tid);
        stage_tile64(B + n0 * EMB + kt, sB, tid);
        __syncthreads();

        #pragma unroll
        for (int kk = 0; kk < 2; ++kk) {
            bf16x8 af[4], bfr[4];
            #pragma unroll
            for (int rt = 0; rt < 4; ++rt)
                af[rt] = *(const bf16x8*)&sA[(wm + rt * 16 + l16) * 64
                         + (((kk << 2) | quad) ^ rsw) * 8];
            #pragma unroll
            for (int ct = 0; ct < 4; ++ct)
                bfr[ct] = *(const bf16x8*)&sB[(wn + ct * 16 + l16) * 64
                          + (((kk << 2) | quad) ^ rsw) * 8];
            if (isv) {
                #pragma unroll
                for (int i = 0; i < 4; ++i)
                    #pragma unroll
                    for (int j = 0; j < 4; ++j)
                        acc[i][j] = __builtin_amdgcn_mfma_f32_16x16x32_bf16(
                            af[i], bfr[j], acc[i][j], 0, 0, 0);
            } else {
                #pragma unroll
                for (int i = 0; i < 4; ++i)
                    #pragma unroll
                    for (int j = 0; j < 4; ++j)
                        acc[i][j] = __builtin_amdgcn_mfma_f32_16x16x32_bf16(
                            bfr[i], af[j], acc[i][j], 0, 0, 0);
            }
        }
    }

    if (!isv) {
        // Q/K swapped layout: acc[i=dimtile][j=toktile]; row=dim d (regs),
        // col=token (l16). Rotary pair in regs (0,1) and (2,3).
        short* C = (blockIdx.z == 0) ? Qb : Kb;
        const float scl = (blockIdx.z == 0) ? SCALE : 1.0f;
        #pragma unroll
        for (int i = 0; i < 4; ++i) {
            const int d0  = (int)(n0) + wn + i * 16 + quad * 4;
            const int hh  = d0 >> 6, dd0 = d0 & (HD - 1);
            const float invf0 = exp2f(-ROPE_COEF * (float)(dd0 >> 1));
            const float invf1 = exp2f(-ROPE_COEF * (float)((dd0 >> 1) + 1));
            #pragma unroll
            for (int j = 0; j < 4; ++j) {
                const int tok = (int)(m0) + wm + j * 16 + l16;
                const int bb = tok >> 11, ss = tok & (SEQ - 1);
                float s0, c0, s1, c1;
                __sincosf((float)ss * invf0, &s0, &c0);
                __sincosf((float)ss * invf1, &s1, &c1);
                const f32x4 x = acc[i][j];
                short4 o4;
                o4.x = f2bf((x[0] * c0 - x[1] * s0) * scl);
                o4.y = f2bf((x[0] * s0 + x[1] * c0) * scl);
                o4.z = f2bf((x[2] * c1 - x[3] * s1) * scl);
                o4.w = f2bf((x[2] * s1 + x[3] * c1) * scl);
                *(short4*)&C[(((long)(bb * NH + hh)) << 17)
                             + ((long)ss << 6) + dd0] = o4;
            }
        }
    } else {
        // V original layout: acc[rt=toktile][ct=dimtile]; rows=tokens in regs.
        // Vt[((b*NH+h)*HD + d)*SEQ + s], short4 along tokens.
        #pragma unroll
        for (int rt = 0; rt < 4; ++rt) {
            #pragma unroll
            for (int ct = 0; ct < 4; ++ct) {
                const long row0 = m0 + wm + rt * 16 + quad * 4;
                const long col  = n0 + wn + ct * 16 + l16;
                const int bb = (int)(row0 >> 11), ss = (int)(row0 & (SEQ - 1));
                const int hh = (int)(col >> 6),   dd = (int)(col & (HD - 1));
                short4 s4;
                s4.x = f2bf(acc[rt][ct][0]); s4.y = f2bf(acc[rt][ct][1]);
                s4.z = f2bf(acc[rt][ct][2]); s4.w = f2bf(acc[rt][ct][3]);
                *(short4*)&Vtb[(((long)(bb * NH + hh)) << 17) + ((long)dd << 11) + ss] = s4;
            }
        }
    }
}

// Output GEMM: out = ctx(bf16) @ Wo^T(bf16), out fp32 [4096,1024]
// 128x64 tiles -> 512 blocks = 2 blocks/CU. Per wave 64x32 output.
__global__ __launch_bounds__(256)
void gemm_out_bf16(const short* __restrict__ Ab, const short* __restrict__ Bb,
                   float* __restrict__ C)
{
    __shared__ short sA[128 * 32];
    __shared__ short sB[64 * 32];

    const int tid  = threadIdx.x;
    const int wave = tid >> 6, lane = tid & 63;
    const int quad = lane >> 4, l16 = lane & 15;
    const int wm = (wave >> 1) * 64, wn = (wave & 1) * 32;
    const long m0 = (long)blockIdx.x * 128, n0 = (long)blockIdx.y * 64;

    f32x4 acc[4][2];
    #pragma unroll
    for (int i = 0; i < 4; ++i)
        #pragma unroll
        for (int j = 0; j < 2; ++j) acc[i][j] = (f32x4){0.f, 0.f, 0.f, 0.f};

    for (int kt = 0; kt < DATTN; kt += 32) {
        __syncthreads();
        stage_tile(Ab + m0 * DATTN + kt, sA, wave, lane);
        // B tile 64x32: one gl_lds16 per thread (rows wave*16.., chunk lane&3)
        gl_lds16(Bb + n0 * DATTN + kt
                     + (long)(wave * 16 + (lane >> 2)) * DATTN + (lane & 3) * 8,
                 sB + wave * 512);
        __syncthreads();

        bf16x8 af[4], bfr[2];
        #pragma unroll
        for (int rt = 0; rt < 4; ++rt)
            af[rt] = *(const bf16x8*)&sA[(wm + rt * 16 + l16) * 32 + quad * 8];
        #pragma unroll
        for (int ct = 0; ct < 2; ++ct)
            bfr[ct] = *(const bf16x8*)&sB[(wn + ct * 16 + l16) * 32 + quad * 8];
        #pragma unroll
        for (int rt = 0; rt < 4; ++rt)
            #pragma unroll
            for (int ct = 0; ct < 2; ++ct)
                acc[rt][ct] = __builtin_amdgcn_mfma_f32_16x16x32_bf16(
                    af[rt], bfr[ct], acc[rt][ct], 0, 0, 0);
    }

    #pragma unroll
    for (int rt = 0; rt < 4; ++rt) {
        #pragma unroll
        for (int ct = 0; ct < 2; ++ct) {
            #pragma unroll
            for (int reg = 0; reg < 4; ++reg) {
                const long row = m0 + wm + rt * 16 + quad * 4 + reg;
                const long col = n0 + wn + ct * 16 + l16;
                C[row * EMB + col] = acc[rt][ct][reg];
            }
        }
    }
}

// ---------------- MFMA flash attention: TQ=128, gl_lds-staged K/V, swizzled ----------------
// 512 blocks; block = (pair p, 128-query tile t); 4 waves x two 16-q groups sharing
// all K/V fragment reads. K/V staged via global_load_lds (16B/lane, linear LDS dest,
// PRE-SWIZZLED global source chunk off^(row&7); reads apply the same XOR — rule-21
// both-sides pattern). Balance: ids 0..255 carry t=8..15 (heavy first), 256..511
// t=0..7 (t_h+t_l=15). XCD pinning: id&7 = residue; 4 pairs/XCD -> K/V L2-resident.
// LDS 50 KB. T5: s_setprio(1) around MFMA clusters.
#define KLD 64   // K/V LDS row stride (shorts) — linear, swizzle in chunk index
#define PLD 72   // P buffer row stride (shorts)

__global__ __launch_bounds__(256, 2)
void flash_attn_mfma(const short* __restrict__ Qb,
                     const short* __restrict__ Kb,
                     const short* __restrict__ Vtb,
                     short* __restrict__ ctx)
{
    // id -> (xcd residue r, pair p, 128-query tile t)
    const int id  = blockIdx.x;           // 0..511
    const int hi  = id >> 8;              // 0 = heavy half, 1 = light half
    const int idx = id & 255;
    const int r   = idx & 7;              // XCD residue
    const int s5  = idx >> 3;             // 0..31
    const int pi  = s5 & 3;               // pair-within-residue
    const int ts8 = s5 >> 2;              // 0..7
    const int p   = r + 8 * pi;           // (b*NH+h) in [0,32)
    const int b   = p >> 4, h = p & 15;
    const int t   = hi ? ts8 : (15 - ts8);

    const int tid = threadIdx.x;
    const int wave = tid >> 6, lane = tid & 63;
    const int quad = lane >> 4, l16 = lane & 15;
    const int r0 = t * 128;

    __shared__ short sk[2 * 64 * KLD];    // [half][row][chunk] linear (16 KB)
    __shared__ short sv[2 * 64 * KLD];    // (16 KB)
    __shared__ short sp[4][32 * PLD];     // per-wave P: rows 0..15 g0, 16..31 g1 (18 KB)

    const long base = ((long)(b * NH + h)) << 17;   // SEQ*HD = 2^17

    // two 16-query groups per wave (contiguous): iq1 = iq0 + 16
    const int iq0 = r0 + wave * 32 + l16;
    const int iq1 = iq0 + 16;
    const int dtile = 2 * t + (wave >> 1);   // this wave's diagonal 64-key tile
    const int rsw = l16 & 7;                 // read-side swizzle (row&7 == l16&7)

    bf16x8 qf0[2], qf1[2];
    #pragma unroll
    for (int tt = 0; tt < 2; ++tt) {
        qf0[tt] = *(const bf16x8*)(Qb + base + (long)iq0 * HD + tt * 32 + quad * 8);
        qf1[tt] = *(const bf16x8*)(Qb + base + (long)iq1 * HD + tt * 32 + quad * 8);
    }

    f32x4 acc0[4], acc1[4];
    #pragma unroll
    for (int ct = 0; ct < 4; ++ct) {
        acc0[ct] = (f32x4){0.f, 0.f, 0.f, 0.f};
        acc1[ct] = (f32x4){0.f, 0.f, 0.f, 0.f};
    }
    float m0 = MINIT, l0 = 0.f;
    float m1 = MINIT, l1 = 0.f;

    const int njt = t + 1;                // 128-key rounds

    #pragma unroll 1
    for (int jt = 0; jt < njt; ++jt) {
        const int jbase = jt * 128;

        __syncthreads();   // previous-round sk/sv reads complete
        #pragma unroll
        for (int c = 0; c < 4; ++c) {
            const int cc   = c * 256 + tid;        // 16B-chunk index 0..1023
            const int half = cc >> 9;
            const int row  = (cc >> 3) & 63;
            const int sch  = (cc & 7) ^ (row & 7); // pre-swizzled source chunk
            // LDS dest: wave-uniform base; HW adds lane*16B -> chunk cc linear
            gl_lds16(Kb + base + (long)(jbase + half * 64 + row) * HD + sch * 8,
                     sk + ((c * 256 + wave * 64) << 3));
            gl_lds16(Vtb + base + ((long)row << 11) + jbase + half * 64 + sch * 8,
                     sv + ((c * 256 + wave * 64) << 3));
        }
        __syncthreads();   // vmcnt(0) drain -> staged data visible

        #pragma unroll
        for (int half = 0; half < 2; ++half) {
            const int jt2 = 2 * jt + half;    // 64-key tile index
            if (jt2 > dtile) continue;        // beyond this wave's causal range
            const int jb2 = jbase + half * 64;
            const short* skh = sk + half * 64 * KLD;
            const short* svh = sv + half * 64 * KLD;

            // S^T for both groups; K fragments per-ct, shared by both groups.
            // Read swizzle: G[row][slot] lives at LDS chunk slot^(row&7).
            f32x4 s0[4], s1[4];
            __builtin_amdgcn_s_setprio(1);
            #pragma unroll
            for (int ct = 0; ct < 4; ++ct) {
                const int rr16 = (ct * 16 + l16) * KLD;
                bf16x8 k0 = *(const bf16x8*)&skh[rr16 + ((quad ^ rsw) << 3)];
                bf16x8 k1 = *(const bf16x8*)&skh[rr16 + (((4 + quad) ^ rsw) << 3)];
                f32x4 z0 = (f32x4){0.f, 0.f, 0.f, 0.f};
                z0 = __builtin_amdgcn_mfma_f32_16x16x32_bf16(k0, qf0[0], z0, 0, 0, 0);
                z0 = __builtin_amdgcn_mfma_f32_16x16x32_bf16(k1, qf0[1], z0, 0, 0, 0);
                s0[ct] = z0;
                f32x4 z1 = (f32x4){0.f, 0.f, 0.f, 0.f};
                z1 = __builtin_amdgcn_mfma_f32_16x16x32_bf16(k0, qf1[0], z1, 0, 0, 0);
                z1 = __builtin_amdgcn_mfma_f32_16x16x32_bf16(k1, qf1[1], z1, 0, 0, 0);
                s1[ct] = z1;
            }
            __builtin_amdgcn_s_setprio(0);

            if (jt2 == dtile) {   // diagonal tile: causal mask per group
                #pragma unroll
                for (int ct = 0; ct < 4; ++ct)
                    #pragma unroll
                    for (int rr = 0; rr < 4; ++rr) {
                        const int j = jb2 + ct * 16 + quad * 4 + rr;
                        if (!((j < iq0) || (iq0 == 0 && j == 0)))
                            s0[ct][rr] = -INFINITY;
                        if (!(j < iq1))               // iq1 >= 16, no (0,0) case
                            s1[ct][rr] = -INFINITY;
                    }
            }

            // online softmax, group 0
            float mx0 = MINIT;
            #pragma unroll
            for (int ct = 0; ct < 4; ++ct)
                #pragma unroll
                for (int rr = 0; rr < 4; ++rr) mx0 = fmaxf(mx0, s0[ct][rr]);
            mx0 = fmaxf(mx0, __shfl_xor(mx0, 16, 64));
            mx0 = fmaxf(mx0, __shfl_xor(mx0, 32, 64));
            const float mn0 = fmaxf(m0, mx0);
            const float a0 = __expf(m0 - mn0);
            m0 = mn0;
            float ss0 = 0.f;
            #pragma unroll
            for (int ct = 0; ct < 4; ++ct)
                #pragma unroll
                for (int rr = 0; rr < 4; ++rr) {
                    const float e = __expf(s0[ct][rr] - mn0);
                    s0[ct][rr] = e;
                    ss0 += e;
                }
            ss0 += __shfl_xor(ss0, 16, 64);
            ss0 += __shfl_xor(ss0, 32, 64);
            l0 = l0 * a0 + ss0;

            // online softmax, group 1
            float mx1 = MINIT;
            #pragma unroll
            for (int ct = 0; ct < 4; ++ct)
                #pragma unroll
                for (int rr = 0; rr < 4; ++rr) mx1 = fmaxf(mx1, s1[ct][rr]);
            mx1 = fmaxf(mx1, __shfl_xor(mx1, 16, 64));
            mx1 = fmaxf(mx1, __shfl_xor(mx1, 32, 64));
            const float mn1 = fmaxf(m1, mx1);
            const float a1 = __expf(m1 - mn1);
            m1 = mn1;
            float ss1 = 0.f;
            #pragma unroll
            for (int ct = 0; ct < 4; ++ct)
                #pragma unroll
                for (int rr = 0; rr < 4; ++rr) {
                    const float e = __expf(s1[ct][rr] - mn1);
                    s1[ct][rr] = e;
                    ss1 += e;
                }
            ss1 += __shfl_xor(ss1, 16, 64);
            ss1 += __shfl_xor(ss1, 32, 64);
            l1 = l1 * a1 + ss1;

            // P0/P1 -> LDS (separate 16-row halves), rescale, combined PV
            short* pw0 = sp[wave];
            short* pw1 = sp[wave] + 16 * PLD;
            #pragma unroll
            for (int ct = 0; ct < 4; ++ct) {
                short4 p4;
                p4.x = f2bf(s0[ct][0]); p4.y = f2bf(s0[ct][1]);
                p4.z = f2bf(s0[ct][2]); p4.w = f2bf(s0[ct][3]);
                *(short4*)&pw0[l16 * PLD + ct * 16 + quad * 4] = p4;
                short4 q4;
                q4.x = f2bf(s1[ct][0]); q4.y = f2bf(s1[ct][1]);
                q4.z = f2bf(s1[ct][2]); q4.w = f2bf(s1[ct][3]);
                *(short4*)&pw1[l16 * PLD + ct * 16 + quad * 4] = q4;
            }

            #pragma unroll
            for (int ct = 0; ct < 4; ++ct)
                #pragma unroll
                for (int rr = 0; rr < 4; ++rr) {
                    acc0[ct][rr] *= a0;
                    acc1[ct][rr] *= a1;
                }

            bf16x8 pf00 = *(const bf16x8*)&pw0[l16 * PLD + quad * 8];
            bf16x8 pf01 = *(const bf16x8*)&pw0[l16 * PLD + 32 + quad * 8];
            bf16x8 pf10 = *(const bf16x8*)&pw1[l16 * PLD + quad * 8];
            bf16x8 pf11 = *(const bf16x8*)&pw1[l16 * PLD + 32 + quad * 8];

            // PV: V fragments per-ct, shared by both groups (same swizzled reads)
            __builtin_amdgcn_s_setprio(1);
            #pragma unroll
            for (int ct = 0; ct < 4; ++ct) {
                const int rr16 = (ct * 16 + l16) * KLD;
                bf16x8 v0 = *(const bf16x8*)&svh[rr16 + ((quad ^ rsw) << 3)];
                bf16x8 v1 = *(const bf16x8*)&svh[rr16 + (((4 + quad) ^ rsw) << 3)];
                acc0[ct] = __builtin_amdgcn_mfma_f32_16x16x32_bf16(
                    v0, pf00, acc0[ct], 0, 0, 0);
                acc0[ct] = __builtin_amdgcn_mfma_f32_16x16x32_bf16(
                    v1, pf01, acc0[ct], 0, 0, 0);
                acc1[ct] = __builtin_amdgcn_mfma_f32_16x16x32_bf16(
                    v0, pf10, acc1[ct], 0, 0, 0);
                acc1[ct] = __builtin_amdgcn_mfma_f32_16x16x32_bf16(
                    v1, pf11, acc1[ct], 0, 0, 0);
            }
            __builtin_amdgcn_s_setprio(0);
        }
    }

    // epilogue: acc C-layout row=dim (ct*16+quad*4+reg), col=l16=query
    {
        const float inv0 = 1.f / l0;
        short* orow = ctx + (long)(b * SEQ + iq0) * DATTN + h * HD;
        #pragma unroll
        for (int ct = 0; ct < 4; ++ct) {
            short4 o4;
            o4.x = f2bf(acc0[ct][0] * inv0);
            o4.y = f2bf(acc0[ct][1] * inv0);
            o4.z = f2bf(acc0[ct][2] * inv0);
            o4.w = f2bf(acc0[ct][3] * inv0);
            *(short4*)&orow[ct * 16 + quad * 4] = o4;
        }
    }
    {
        const float inv1 = 1.f / l1;
        short* orow = ctx + (long)(b * SEQ + iq1) * DATTN + h * HD;
        #pragma unroll
        for (int ct = 0; ct < 4; ++ct) {
            short4 o4;
            o4.x = f2bf(acc1[ct][0] * inv1);
            o4.y = f2bf(acc1[ct][1] * inv1);
            o4.z = f2bf(acc1[ct][2] * inv1);
            o4.w = f2bf(acc1[ct][3] * inv1);
            *(short4*)&orow[ct * 16 + quad * 4] = o4;
        }
    }
}

extern "C" void kernel_launch(void* const* d_in, const int* in_sizes, int n_in,
                              void* d_out, int out_size, void* d_ws, size_t ws_size,
                              hipStream_t stream) {
    const float* q  = (const float*)d_in[0];
    const float* k  = (const float*)d_in[1];
    const float* v  = (const float*)d_in[2];
    const float* Wq = (const float*)d_in[3];
    const float* Wk = (const float*)d_in[4];
    const float* Wv = (const float*)d_in[5];
    const float* Wo = (const float*)d_in[6];
    float* out = (float*)d_out;

    // workspace (bf16 shorts), 64 MB:
    // qb|kb|vb (4M shorts each) | wqb|wkb|wvb|wob (1M each) | Qb|Kb|Vtb|ctx (4M each)
    const long QKV = (long)MM * EMB;      // 4,194,304
    const long WSZ = (long)DATTN * EMB;   // 1,048,576
    short* basep = (short*)d_ws;
    short* qb  = basep;
    short* kb  = qb + QKV;
    short* vb  = kb + QKV;
    short* wqb = vb + QKV;
    short* wkb = wqb + WSZ;
    short* wvb = wkb + WSZ;
    short* wob = wvb + WSZ;
    short* Qb  = wob + WSZ;
    short* Kb  = Qb + QKV;
    short* Vtb = Kb + QKV;
    short* ctx = Vtb + QKV;

    // 1) fp32 -> bf16 pre-convert
    cvt_all<<<16384, 256, 0, stream>>>(q, k, v, Wq, Wk, Wv, Wo, qb);

    // 2) fused Q/K/V projection + RoPE (BK=64, swizzled staging, in-lane RoPE)
    gemm_proj_bf16<<<dim3(MM / 128, DATTN / 128, 3), 256, 0, stream>>>(
        qb, kb, vb, wqb, wkb, wvb, Qb, Kb, Vtb);

    // 3) flash attention (TQ=128 dual-group, gl_lds-staged, 512 blocks)
    flash_attn_mfma<<<512, 256, 0, stream>>>(Qb, Kb, Vtb, ctx);

    // 4) output GEMM (128x64 tiles -> 512 blocks = 2/CU)
    gemm_out_bf16<<<dim3(MM / 128, EMB / 64), 256, 0, stream>>>(ctx, wob, out);
}

// Round 5
// 211.038 us; speedup vs baseline: 1.3003x; 1.0161x over previous
//
#include <hip/hip_runtime.h>
#include <hip/hip_bf16.h>

// Problem constants (fixed shapes)
#define BATCH 2
#define SEQ   2048
#define EMB   1024
#define DATTN 1024
#define NH    16
#define HD    64
#define MM    (BATCH*SEQ)        // 4096 rows
#define SCALE 0.03125f           // 1/sqrt(1024), exact power of 2
#define MINIT -1.0e30f
#define ROPE_COEF 0.41524101186f // (2/64)*log2(10000)

using bf16x8 = __attribute__((ext_vector_type(8))) short;   // 8 bf16 (4 VGPRs)
using f32x4  = __attribute__((ext_vector_type(4))) float;   // MFMA C/D

__device__ inline short f2bf(float x) {
    __hip_bfloat16 b = __float2bfloat16(x);
    return *reinterpret_cast<short*>(&b);
}

// async global->LDS, 16 B per lane (wave-uniform LDS base). [m03/m97]
__device__ inline void gl_lds16(const short* g, short* l) {
    __builtin_amdgcn_global_load_lds(
        (const __attribute__((address_space(1))) unsigned int*)g,
        (__attribute__((address_space(3))) unsigned int*)l, 16, 0, 0);
}

// ---------------- fp32 -> bf16 pre-convert (q,k,v,Wq,Wk,Wv,Wo) ----------------
__global__ __launch_bounds__(256)
void cvt_all(const float* __restrict__ q, const float* __restrict__ k,
             const float* __restrict__ v,
             const float* __restrict__ Wq, const float* __restrict__ Wk,
             const float* __restrict__ Wv, const float* __restrict__ Wo,
             short* __restrict__ dst)
{
    const long QKV = (long)MM * EMB;      // 4,194,304
    const long WSZ = (long)DATTN * EMB;   // 1,048,576
    const long i = ((long)blockIdx.x * 256 + threadIdx.x) * 4;
    const float* s;
    long off;
    if (i < 3 * QKV) {
        const int seg = (int)(i / QKV);
        off = i - (long)seg * QKV;
        s = (seg == 0) ? q : (seg == 1) ? k : v;
    } else {
        const long j = i - 3 * QKV;
        const int seg = (int)(j / WSZ);
        off = j - (long)seg * WSZ;
        s = (seg == 0) ? Wq : (seg == 1) ? Wk : (seg == 2) ? Wv : Wo;
    }
    float4 x = *(const float4*)(s + off);
    short4 y;
    y.x = f2bf(x.x); y.y = f2bf(x.y); y.z = f2bf(x.z); y.w = f2bf(x.w);
    *(short4*)(dst + i) = y;
}

// ---------------- staging helpers ----------------
// BK=64 staging: 128x64 tile, linear LDS dest, XOR pre-swizzled source chunk
// slot^(row&7) (rule-21 both-sides; reads apply the same XOR -> 2-way = free).
__device__ inline void stage_tile64(const short* g, short* lds, int tid) {
    #pragma unroll
    for (int c = 0; c < 4; ++c) {
        const int cc   = c * 256 + tid;       // 16B-chunk index 0..1023
        const int row  = cc >> 3;             // 0..127
        const int slot = cc & 7;              // 0..7
        const int ssl  = slot ^ (row & 7);    // pre-swizzled source chunk
        gl_lds16(g + (long)row * EMB + ssl * 8, lds + ((cc & ~63) << 3));
    }
}

// 64x64 tile variant (512 chunks, 2 per thread), same swizzle.
__device__ inline void stage_tile64h(const short* g, short* lds, int tid) {
    #pragma unroll
    for (int c = 0; c < 2; ++c) {
        const int cc   = c * 256 + tid;       // 0..511
        const int row  = cc >> 3;             // 0..63
        const int ssl  = (cc & 7) ^ (row & 7);
        gl_lds16(g + (long)row * EMB + ssl * 8, lds + ((cc & ~63) << 3));
    }
}

// ---------------- fused Q/K/V projection, BK=64, RoPE epilogue ----------------
// 128x128 tile, 16 K-steps. Q/K compute C^T (mfma(bfr,af)) so the rotary pair is
// IN-LANE (regs 0/1, 2/3): no shfl, 2 sincos per 4 elems, aligned short4 stores.
__global__ __launch_bounds__(256)
void gemm_proj_bf16(const short* __restrict__ qb, const short* __restrict__ kb,
                    const short* __restrict__ vb,
                    const short* __restrict__ wqb, const short* __restrict__ wkb,
                    const short* __restrict__ wvb,
                    short* __restrict__ Qb, short* __restrict__ Kb,
                    short* __restrict__ Vtb)
{
    const short* A; const short* B;
    if (blockIdx.z == 0)      { A = qb; B = wqb; }
    else if (blockIdx.z == 1) { A = kb; B = wkb; }
    else                      { A = vb; B = wvb; }
    const bool isv = (blockIdx.z == 2);

    __shared__ short sA[128 * 64];   // 16 KB
    __shared__ short sB[128 * 64];   // 16 KB

    const int tid  = threadIdx.x;
    const int wave = tid >> 6, lane = tid & 63;
    const int quad = lane >> 4, l16 = lane & 15;
    const int wm = (wave >> 1) * 64, wn = (wave & 1) * 64;
    const long m0 = (long)blockIdx.x * 128, n0 = (long)blockIdx.y * 128;
    const int rsw = l16 & 7;         // read-side swizzle (row&7 == l16&7)

    f32x4 acc[4][4];
    #pragma unroll
    for (int i = 0; i < 4; ++i)
        #pragma unroll
        for (int j = 0; j < 4; ++j) acc[i][j] = (f32x4){0.f, 0.f, 0.f, 0.f};

    for (int kt = 0; kt < EMB; kt += 64) {
        __syncthreads();
        stage_tile64(A + m0 * EMB + kt, sA, tid);
        stage_tile64(B + n0 * EMB + kt, sB, tid);
        __syncthreads();

        #pragma unroll
        for (int kk = 0; kk < 2; ++kk) {
            bf16x8 af[4], bfr[4];
            #pragma unroll
            for (int rt = 0; rt < 4; ++rt)
                af[rt] = *(const bf16x8*)&sA[(wm + rt * 16 + l16) * 64
                         + (((kk << 2) | quad) ^ rsw) * 8];
            #pragma unroll
            for (int ct = 0; ct < 4; ++ct)
                bfr[ct] = *(const bf16x8*)&sB[(wn + ct * 16 + l16) * 64
                          + (((kk << 2) | quad) ^ rsw) * 8];
            if (isv) {
                #pragma unroll
                for (int i = 0; i < 4; ++i)
                    #pragma unroll
                    for (int j = 0; j < 4; ++j)
                        acc[i][j] = __builtin_amdgcn_mfma_f32_16x16x32_bf16(
                            af[i], bfr[j], acc[i][j], 0, 0, 0);
            } else {
                #pragma unroll
                for (int i = 0; i < 4; ++i)
                    #pragma unroll
                    for (int j = 0; j < 4; ++j)
                        acc[i][j] = __builtin_amdgcn_mfma_f32_16x16x32_bf16(
                            bfr[i], af[j], acc[i][j], 0, 0, 0);
            }
        }
    }

    if (!isv) {
        // Q/K swapped layout: acc[i=dimtile][j=toktile]; row=dim d (regs),
        // col=token (l16). Rotary pair in regs (0,1) and (2,3).
        short* C = (blockIdx.z == 0) ? Qb : Kb;
        const float scl = (blockIdx.z == 0) ? SCALE : 1.0f;
        #pragma unroll
        for (int i = 0; i < 4; ++i) {
            const int d0  = (int)(n0) + wn + i * 16 + quad * 4;
            const int hh  = d0 >> 6, dd0 = d0 & (HD - 1);
            const float invf0 = exp2f(-ROPE_COEF * (float)(dd0 >> 1));
            const float invf1 = exp2f(-ROPE_COEF * (float)((dd0 >> 1) + 1));
            #pragma unroll
            for (int j = 0; j < 4; ++j) {
                const int tok = (int)(m0) + wm + j * 16 + l16;
                const int bb = tok >> 11, ss = tok & (SEQ - 1);
                float s0, c0, s1, c1;
                __sincosf((float)ss * invf0, &s0, &c0);
                __sincosf((float)ss * invf1, &s1, &c1);
                const f32x4 x = acc[i][j];
                short4 o4;
                o4.x = f2bf((x[0] * c0 - x[1] * s0) * scl);
                o4.y = f2bf((x[0] * s0 + x[1] * c0) * scl);
                o4.z = f2bf((x[2] * c1 - x[3] * s1) * scl);
                o4.w = f2bf((x[2] * s1 + x[3] * c1) * scl);
                *(short4*)&C[(((long)(bb * NH + hh)) << 17)
                             + ((long)ss << 6) + dd0] = o4;
            }
        }
    } else {
        // V original layout: acc[rt=toktile][ct=dimtile]; rows=tokens in regs.
        // Vt[((b*NH+h)*HD + d)*SEQ + s], short4 along tokens.
        #pragma unroll
        for (int rt = 0; rt < 4; ++rt) {
            #pragma unroll
            for (int ct = 0; ct < 4; ++ct) {
                const long row0 = m0 + wm + rt * 16 + quad * 4;
                const long col  = n0 + wn + ct * 16 + l16;
                const int bb = (int)(row0 >> 11), ss = (int)(row0 & (SEQ - 1));
                const int hh = (int)(col >> 6),   dd = (int)(col & (HD - 1));
                short4 s4;
                s4.x = f2bf(acc[rt][ct][0]); s4.y = f2bf(acc[rt][ct][1]);
                s4.z = f2bf(acc[rt][ct][2]); s4.w = f2bf(acc[rt][ct][3]);
                *(short4*)&Vtb[(((long)(bb * NH + hh)) << 17) + ((long)dd << 11) + ss] = s4;
            }
        }
    }
}

// Output GEMM: out = ctx(bf16) @ Wo^T(bf16), out fp32 [4096,1024]
// 128x64 tiles -> 512 blocks = 2/CU; BK=64 + XOR swizzle (proj-verified pattern):
// 16 K-steps instead of 32 -> half the barrier drains; conflict-free reads.
__global__ __launch_bounds__(256)
void gemm_out_bf16(const short* __restrict__ Ab, const short* __restrict__ Bb,
                   float* __restrict__ C)
{
    __shared__ short sA[128 * 64];   // 16 KB
    __shared__ short sB[64 * 64];    // 8 KB

    const int tid  = threadIdx.x;
    const int wave = tid >> 6, lane = tid & 63;
    const int quad = lane >> 4, l16 = lane & 15;
    const int wm = (wave >> 1) * 64, wn = (wave & 1) * 32;
    const long m0 = (long)blockIdx.x * 128, n0 = (long)blockIdx.y * 64;
    const int rsw = l16 & 7;

    f32x4 acc[4][2];
    #pragma unroll
    for (int i = 0; i < 4; ++i)
        #pragma unroll
        for (int j = 0; j < 2; ++j) acc[i][j] = (f32x4){0.f, 0.f, 0.f, 0.f};

    for (int kt = 0; kt < DATTN; kt += 64) {
        __syncthreads();
        stage_tile64(Ab + m0 * DATTN + kt, sA, tid);
        stage_tile64h(Bb + n0 * DATTN + kt, sB, tid);
        __syncthreads();

        #pragma unroll
        for (int kk = 0; kk < 2; ++kk) {
            bf16x8 af[4], bfr[2];
            #pragma unroll
            for (int rt = 0; rt < 4; ++rt)
                af[rt] = *(const bf16x8*)&sA[(wm + rt * 16 + l16) * 64
                         + (((kk << 2) | quad) ^ rsw) * 8];
            #pragma unroll
            for (int ct = 0; ct < 2; ++ct)
                bfr[ct] = *(const bf16x8*)&sB[(wn + ct * 16 + l16) * 64
                          + (((kk << 2) | quad) ^ rsw) * 8];
            #pragma unroll
            for (int rt = 0; rt < 4; ++rt)
                #pragma unroll
                for (int ct = 0; ct < 2; ++ct)
                    acc[rt][ct] = __builtin_amdgcn_mfma_f32_16x16x32_bf16(
                        af[rt], bfr[ct], acc[rt][ct], 0, 0, 0);
        }
    }

    #pragma unroll
    for (int rt = 0; rt < 4; ++rt) {
        #pragma unroll
        for (int ct = 0; ct < 2; ++ct) {
            #pragma unroll
            for (int reg = 0; reg < 4; ++reg) {
                const long row = m0 + wm + rt * 16 + quad * 4 + reg;
                const long col = n0 + wn + ct * 16 + l16;
                C[row * EMB + col] = acc[rt][ct][reg];
            }
        }
    }
}

// ---------------- MFMA flash attention: TQ=128, dbuf 64-key pipeline ----------------
// 512 blocks; block = (pair p, 128-query tile t); 4 waves x two contiguous 16-q
// groups sharing all K/V fragment reads. NEW (R5): 2-deep double-buffered staging
// over 64-key tiles with raw s_barrier + own-wave vmcnt(0): loads for tile j+1
// issue right after tile j's barrier and retire under tile j's compute -> no
// barrier carries exposed memory latency (T3/T4-lite). One barrier per tile.
// Safety: buf[p] is overwritten only after the NEXT barrier, which any wave
// reaches only after its buf[p] ds_reads retired into regs (lgkm before MFMA).
// Balance: ids 0..255 carry t=8..15 (heavy first), 256..511 t=0..7.
// XCD pinning: id&7 = residue; 4 pairs/XCD -> K/V L2-resident. LDS 50 KB.
#define KLD 64   // K/V LDS row stride (shorts) — linear, swizzle in chunk index
#define PLD 72   // P buffer row stride (shorts)

// stage one 64-key tile of K and V (512 chunks each, 2+2 gl_lds per thread)
__device__ inline void stage_kv64(const short* __restrict__ Kb,
                                  const short* __restrict__ Vtb,
                                  long base, int jb2,
                                  short* skp, short* svp,
                                  int tid, int wave)
{
    #pragma unroll
    for (int c = 0; c < 2; ++c) {
        const int cc  = c * 256 + tid;        // 0..511
        const int row = cc >> 3;              // 0..63
        const int sch = (cc & 7) ^ (row & 7); // pre-swizzled source chunk
        short* dk = skp + ((c * 256 + (tid & ~63)) << 3) - ((tid & ~63) << 3)
                        + (((c * 256 + tid) & ~63) - (c * 256 + tid - (tid & 63)) ) ; // (unused form)
        (void)dk;
        // LDS dest: wave-uniform chunk base (c*256 + wave*64); HW adds lane*16B.
        gl_lds16(Kb + base + (long)(jb2 + row) * HD + sch * 8,
                 skp + ((c * 256 + wave * 64) << 3));
        gl_lds16(Vtb + base + ((long)row << 11) + jb2 + sch * 8,
                 svp + ((c * 256 + wave * 64) << 3));
    }
}

__global__ __launch_bounds__(256, 3)
void flash_attn_mfma(const short* __restrict__ Qb,
                     const short* __restrict__ Kb,
                     const short* __restrict__ Vtb,
                     short* __restrict__ ctx)
{
    // id -> (xcd residue r, pair p, 128-query tile t)
    const int id  = blockIdx.x;           // 0..511
    const int hi  = id >> 8;              // 0 = heavy half, 1 = light half
    const int idx = id & 255;
    const int r   = idx & 7;              // XCD residue
    const int s5  = idx >> 3;             // 0..31
    const int pi  = s5 & 3;               // pair-within-residue
    const int ts8 = s5 >> 2;              // 0..7
    const int p   = r + 8 * pi;           // (b*NH+h) in [0,32)
    const int b   = p >> 4, h = p & 15;
    const int t   = hi ? ts8 : (15 - ts8);

    const int tid = threadIdx.x;
    const int wave = tid >> 6, lane = tid & 63;
    const int quad = lane >> 4, l16 = lane & 15;
    const int r0 = t * 128;

    __shared__ short sk[2][64 * KLD];     // double-buffered K (16 KB)
    __shared__ short sv[2][64 * KLD];     // double-buffered V (16 KB)
    __shared__ short sp[4][32 * PLD];     // per-wave P: rows 0..15 g0, 16..31 g1 (18 KB)

    const long base = ((long)(b * NH + h)) << 17;   // SEQ*HD = 2^17

    // two 16-query groups per wave (contiguous): iq1 = iq0 + 16
    const int iq0 = r0 + wave * 32 + l16;
    const int iq1 = iq0 + 16;
    const int dtile = 2 * t + (wave >> 1);   // this wave's diagonal 64-key tile
    const int rsw = l16 & 7;                 // read-side swizzle (row&7 == l16&7)

    bf16x8 qf0[2], qf1[2];
    #pragma unroll
    for (int tt = 0; tt < 2; ++tt) {
        qf0[tt] = *(const bf16x8*)(Qb + base + (long)iq0 * HD + tt * 32 + quad * 8);
        qf1[tt] = *(const bf16x8*)(Qb + base + (long)iq1 * HD + tt * 32 + quad * 8);
    }

    f32x4 acc0[4], acc1[4];
    #pragma unroll
    for (int ct = 0; ct < 4; ++ct) {
        acc0[ct] = (f32x4){0.f, 0.f, 0.f, 0.f};
        acc1[ct] = (f32x4){0.f, 0.f, 0.f, 0.f};
    }
    float m0 = MINIT, l0 = 0.f;
    float m1 = MINIT, l1 = 0.f;

    const int J = 2 * t + 2;              // 64-key tiles to process (block-uniform)

    stage_kv64(Kb, Vtb, base, 0, sk[0], sv[0], tid, wave);

    #pragma unroll 1
    for (int j2 = 0; j2 < J; ++j2) {
        const int pb = j2 & 1;
        // own loads of buf[pb] (issued a full tile ago) complete, then sync:
        asm volatile("s_waitcnt vmcnt(0)" ::: "memory");
        __builtin_amdgcn_s_barrier();
        // issue next tile's loads into the other buffer (retire under compute)
        if (j2 + 1 < J)
            stage_kv64(Kb, Vtb, base, (j2 + 1) * 64,
                       sk[pb ^ 1], sv[pb ^ 1], tid, wave);

        if (j2 <= dtile) {
            const int jb2 = j2 * 64;
            const short* skh = sk[pb];
            const short* svh = sv[pb];

            // S^T for both groups; K fragments per-ct, shared by both groups.
            f32x4 s0[4], s1[4];
            __builtin_amdgcn_s_setprio(1);
            #pragma unroll
            for (int ct = 0; ct < 4; ++ct) {
                const int rr16 = (ct * 16 + l16) * KLD;
                bf16x8 k0 = *(const bf16x8*)&skh[rr16 + ((quad ^ rsw) << 3)];
                bf16x8 k1 = *(const bf16x8*)&skh[rr16 + (((4 + quad) ^ rsw) << 3)];
                f32x4 z0 = (f32x4){0.f, 0.f, 0.f, 0.f};
                z0 = __builtin_amdgcn_mfma_f32_16x16x32_bf16(k0, qf0[0], z0, 0, 0, 0);
                z0 = __builtin_amdgcn_mfma_f32_16x16x32_bf16(k1, qf0[1], z0, 0, 0, 0);
                s0[ct] = z0;
                f32x4 z1 = (f32x4){0.f, 0.f, 0.f, 0.f};
                z1 = __builtin_amdgcn_mfma_f32_16x16x32_bf16(k0, qf1[0], z1, 0, 0, 0);
                z1 = __builtin_amdgcn_mfma_f32_16x16x32_bf16(k1, qf1[1], z1, 0, 0, 0);
                s1[ct] = z1;
            }
            __builtin_amdgcn_s_setprio(0);

            if (j2 == dtile) {   // diagonal tile: causal mask per group
                #pragma unroll
                for (int ct = 0; ct < 4; ++ct)
                    #pragma unroll
                    for (int rr = 0; rr < 4; ++rr) {
                        const int j = jb2 + ct * 16 + quad * 4 + rr;
                        if (!((j < iq0) || (iq0 == 0 && j == 0)))
                            s0[ct][rr] = -INFINITY;
                        if (!(j < iq1))               // iq1 >= 16, no (0,0) case
                            s1[ct][rr] = -INFINITY;
                    }
            }

            // online softmax, group 0
            float mx0 = MINIT;
            #pragma unroll
            for (int ct = 0; ct < 4; ++ct)
                #pragma unroll
                for (int rr = 0; rr < 4; ++rr) mx0 = fmaxf(mx0, s0[ct][rr]);
            mx0 = fmaxf(mx0, __shfl_xor(mx0, 16, 64));
            mx0 = fmaxf(mx0, __shfl_xor(mx0, 32, 64));
            const float mn0 = fmaxf(m0, mx0);
            const float a0 = __expf(m0 - mn0);
            m0 = mn0;
            float ss0 = 0.f;
            #pragma unroll
            for (int ct = 0; ct < 4; ++ct)
                #pragma unroll
                for (int rr = 0; rr < 4; ++rr) {
                    const float e = __expf(s0[ct][rr] - mn0);
                    s0[ct][rr] = e;
                    ss0 += e;
                }
            ss0 += __shfl_xor(ss0, 16, 64);
            ss0 += __shfl_xor(ss0, 32, 64);
            l0 = l0 * a0 + ss0;

            // online softmax, group 1
            float mx1 = MINIT;
            #pragma unroll
            for (int ct = 0; ct < 4; ++ct)
                #pragma unroll
                for (int rr = 0; rr < 4; ++rr) mx1 = fmaxf(mx1, s1[ct][rr]);
            mx1 = fmaxf(mx1, __shfl_xor(mx1, 16, 64));
            mx1 = fmaxf(mx1, __shfl_xor(mx1, 32, 64));
            const float mn1 = fmaxf(m1, mx1);
            const float a1 = __expf(m1 - mn1);
            m1 = mn1;
            float ss1 = 0.f;
            #pragma unroll
            for (int ct = 0; ct < 4; ++ct)
                #pragma unroll
                for (int rr = 0; rr < 4; ++rr) {
                    const float e = __expf(s1[ct][rr] - mn1);
                    s1[ct][rr] = e;
                    ss1 += e;
                }
            ss1 += __shfl_xor(ss1, 16, 64);
            ss1 += __shfl_xor(ss1, 32, 64);
            l1 = l1 * a1 + ss1;

            // P0/P1 -> LDS (per-wave buffer), rescale, combined PV
            short* pw0 = sp[wave];
            short* pw1 = sp[wave] + 16 * PLD;
            #pragma unroll
            for (int ct = 0; ct < 4; ++ct) {
                short4 p4;
                p4.x = f2bf(s0[ct][0]); p4.y = f2bf(s0[ct][1]);
                p4.z = f2bf(s0[ct][2]); p4.w = f2bf(s0[ct][3]);
                *(short4*)&pw0[l16 * PLD + ct * 16 + quad * 4] = p4;
                short4 q4;
                q4.x = f2bf(s1[ct][0]); q4.y = f2bf(s1[ct][1]);
                q4.z = f2bf(s1[ct][2]); q4.w = f2bf(s1[ct][3]);
                *(short4*)&pw1[l16 * PLD + ct * 16 + quad * 4] = q4;
            }

            #pragma unroll
            for (int ct = 0; ct < 4; ++ct)
                #pragma unroll
                for (int rr = 0; rr < 4; ++rr) {
                    acc0[ct][rr] *= a0;
                    acc1[ct][rr] *= a1;
                }

            bf16x8 pf00 = *(const bf16x8*)&pw0[l16 * PLD + quad * 8];
            bf16x8 pf01 = *(const bf16x8*)&pw0[l16 * PLD + 32 + quad * 8];
            bf16x8 pf10 = *(const bf16x8*)&pw1[l16 * PLD + quad * 8];
            bf16x8 pf11 = *(const bf16x8*)&pw1[l16 * PLD + 32 + quad * 8];

            // PV: V fragments per-ct, shared by both groups (same swizzled reads)
            __builtin_amdgcn_s_setprio(1);
            #pragma unroll
            for (int ct = 0; ct < 4; ++ct) {
                const int rr16 = (ct * 16 + l16) * KLD;
                bf16x8 v0 = *(const bf16x8*)&svh[rr16 + ((quad ^ rsw) << 3)];
                bf16x8 v1 = *(const bf16x8*)&svh[rr16 + (((4 + quad) ^ rsw) << 3)];
                acc0[ct] = __builtin_amdgcn_mfma_f32_16x16x32_bf16(
                    v0, pf00, acc0[ct], 0, 0, 0);
                acc0[ct] = __builtin_amdgcn_mfma_f32_16x16x32_bf16(
                    v1, pf01, acc0[ct], 0, 0, 0);
                acc1[ct] = __builtin_amdgcn_mfma_f32_16x16x32_bf16(
                    v0, pf10, acc1[ct], 0, 0, 0);
                acc1[ct] = __builtin_amdgcn_mfma_f32_16x16x32_bf16(
                    v1, pf11, acc1[ct], 0, 0, 0);
            }
            __builtin_amdgcn_s_setprio(0);
        }
    }

    // epilogue: acc C-layout row=dim (ct*16+quad*4+reg), col=l16=query
    {
        const float inv0 = 1.f / l0;
        short* orow = ctx + (long)(b * SEQ + iq0) * DATTN + h * HD;
        #pragma unroll
        for (int ct = 0; ct < 4; ++ct) {
            short4 o4;
            o4.x = f2bf(acc0[ct][0] * inv0);
            o4.y = f2bf(acc0[ct][1] * inv0);
            o4.z = f2bf(acc0[ct][2] * inv0);
            o4.w = f2bf(acc0[ct][3] * inv0);
            *(short4*)&orow[ct * 16 + quad * 4] = o4;
        }
    }
    {
        const float inv1 = 1.f / l1;
        short* orow = ctx + (long)(b * SEQ + iq1) * DATTN + h * HD;
        #pragma unroll
        for (int ct = 0; ct < 4; ++ct) {
            short4 o4;
            o4.x = f2bf(acc1[ct][0] * inv1);
            o4.y = f2bf(acc1[ct][1] * inv1);
            o4.z = f2bf(acc1[ct][2] * inv1);
            o4.w = f2bf(acc1[ct][3] * inv1);
            *(short4*)&orow[ct * 16 + quad * 4] = o4;
        }
    }
}

extern "C" void kernel_launch(void* const* d_in, const int* in_sizes, int n_in,
                              void* d_out, int out_size, void* d_ws, size_t ws_size,
                              hipStream_t stream) {
    const float* q  = (const float*)d_in[0];
    const float* k  = (const float*)d_in[1];
    const float* v  = (const float*)d_in[2];
    const float* Wq = (const float*)d_in[3];
    const float* Wk = (const float*)d_in[4];
    const float* Wv = (const float*)d_in[5];
    const float* Wo = (const float*)d_in[6];
    float* out = (float*)d_out;

    // workspace (bf16 shorts), 64 MB:
    // qb|kb|vb (4M shorts each) | wqb|wkb|wvb|wob (1M each) | Qb|Kb|Vtb|ctx (4M each)
    const long QKV = (long)MM * EMB;      // 4,194,304
    const long WSZ = (long)DATTN * EMB;   // 1,048,576
    short* basep = (short*)d_ws;
    short* qb  = basep;
    short* kb  = qb + QKV;
    short* vb  = kb + QKV;
    short* wqb = vb + QKV;
    short* wkb = wqb + WSZ;
    short* wvb = wkb + WSZ;
    short* wob = wvb + WSZ;
    short* Qb  = wob + WSZ;
    short* Kb  = Qb + QKV;
    short* Vtb = Kb + QKV;
    short* ctx = Vtb + QKV;

    // 1) fp32 -> bf16 pre-convert
    cvt_all<<<16384, 256, 0, stream>>>(q, k, v, Wq, Wk, Wv, Wo, qb);

    // 2) fused Q/K/V projection + RoPE (BK=64, swizzled staging, in-lane RoPE)
    gemm_proj_bf16<<<dim3(MM / 128, DATTN / 128, 3), 256, 0, stream>>>(
        qb, kb, vb, wqb, wkb, wvb, Qb, Kb, Vtb);

    // 3) flash attention (TQ=128 dual-group, dbuf 64-key pipeline, 512 blocks)
    flash_attn_mfma<<<512, 256, 0, stream>>>(Qb, Kb, Vtb, ctx);

    // 4) output GEMM (128x64 tiles, BK=64 swizzled -> 512 blocks = 2/CU)
    gemm_out_bf16<<<dim3(MM / 128, EMB / 64), 256, 0, stream>>>(ctx, wob, out);
}